// Round 9
// baseline (639.277 us; speedup 1.0000x reference)
//
#include <hip/hip_runtime.h>
#include <hip/hip_bf16.h>

#define NTOK 8192      // B*T
#define CDIM 256
#define TDIM 2048
#define BDIM 4
#define HDIM 8
#define HSZ  32
#define LNUM 4
#define BUF  (NTOK*CDIM)
#define QSTR 768       // fused qkv row stride
#define LC   0.0901684400056f   // 2^-4 * log2(e), folded into Wq/bq

typedef __attribute__((ext_vector_type(8))) short short8v;
typedef __attribute__((ext_vector_type(4))) short short4v;
typedef __attribute__((ext_vector_type(4))) float float4v;

static __device__ __forceinline__ short f2bs(float f){
  union { float f; unsigned u; } x; x.f = f;
  unsigned r = x.u + 0x7FFFu + ((x.u >> 16) & 1u);
  return (short)(r >> 16);
}
static __device__ __forceinline__ float bs2f(short s){
  union { unsigned u; float f; } x; x.u = ((unsigned)(unsigned short)s) << 16;
  return x.f;
}
// pack two fp32 -> bf16x2 (RNE); low = a, high = b
static __device__ __forceinline__ unsigned pkbf(float a, float b){
  union { float f; unsigned u; } x, y; x.f = a; y.f = b;
  unsigned ra = x.u + 0x7FFFu + ((x.u >> 16) & 1u);
  unsigned rb = y.u + 0x7FFFu + ((y.u >> 16) & 1u);
  return __builtin_amdgcn_perm(rb, ra, 0x07060302u);
}
#if __has_builtin(__builtin_amdgcn_exp2f)
static __device__ __forceinline__ float fexp2(float x){ return __builtin_amdgcn_exp2f(x); }
#else
static __device__ __forceinline__ float fexp2(float x){ return __expf(x*0.6931471805599453f); }
#endif

#if __has_builtin(__builtin_amdgcn_mfma_f32_16x16x16bf16_1k)
static __device__ __forceinline__ float4v mfma16(short4v a, short4v b, float4v c){
  return __builtin_amdgcn_mfma_f32_16x16x16bf16_1k(a, b, c, 0, 0, 0);
}
#else
static __device__ __forceinline__ float4v mfma16(short4v a, short4v b, float4v c){
  float4v d;
  asm volatile("v_mfma_f32_16x16x16_bf16 %0, %1, %2, %3\n\ts_nop 7\n\ts_nop 7"
               : "=v"(d) : "v"(a), "v"(b), "v"(c));
  return d;
}
#endif
static __device__ __forceinline__ float4v mfma32(short8v a, short8v b, float4v c){
  return __builtin_amdgcn_mfma_f32_16x16x32_bf16(a, b, c, 0, 0, 0);
}

// ---------------- weight prep: transpose to bf16 [N][K], folding LN gains + softmax scale ----
__global__ __launch_bounds__(256) void k_prep(
    const float* __restrict__ Wq, const float* __restrict__ Wk, const float* __restrict__ Wv,
    const float* __restrict__ Wp, const float* __restrict__ W1, const float* __restrict__ W2,
    const float* __restrict__ l1g, const float* __restrict__ l2g,
    short* __restrict__ qkvT, short* __restrict__ wpT, short* __restrict__ w1T, short* __restrict__ w2T) {
  __shared__ float tile[64][65];
  const int tid = threadIdx.x;
  int id = blockIdx.x;
  int l = id / 96, rr = id % 96;
  const float* src; short* dst; int n0, k0; bool qkvmode; int gsel; float nscale = 1.f;
  if (rr < 48) {
    int tn = rr >> 2, tk = rr & 3;
    n0 = tn*64; k0 = tk*64;
    const float* b3 = (n0 < 256) ? Wq : (n0 < 512 ? Wk : Wv);
    src = b3 + l*65536;
    dst = qkvT + (size_t)l*QSTR*256;
    qkvmode = true; gsel = 1;
    if (n0 < 256) nscale = LC;              // fold softmax scale into Q weights
  } else {
    int r2 = rr - 48;
    int mat = r2 >> 4, t = r2 & 15;
    int tn = t >> 2, tk = t & 3;
    n0 = tn*64; k0 = tk*64;
    const float* b3 = (mat == 0) ? Wp : (mat == 1 ? W1 : W2);
    src = b3 + l*65536;
    dst = (mat == 0 ? wpT : (mat == 1 ? w1T : w2T)) + l*65536;
    qkvmode = false; gsel = (mat == 1) ? 2 : 0;
  }
  const int cn = tid & 63, rk = tid >> 6;
  #pragma unroll
  for (int i = 0; i < 16; ++i) {
    int kk = rk + i*4;
    int n = n0 + cn, k = k0 + kk;
    float v;
    if (qkvmode) { int nn = n & 255; v = src[((nn>>5)*256 + k)*32 + (nn & 31)]; }
    else         { v = src[k*256 + n]; }
    if (gsel == 1)      v *= l1g[l*256 + k];
    else if (gsel == 2) v *= l2g[l*256 + k];
    tile[kk][cn] = v;
  }
  __syncthreads();
  #pragma unroll
  for (int i = 0; i < 16; ++i) {
    int nn = rk + i*4;
    dst[(size_t)(n0 + nn)*256 + k0 + cn] = f2bs(tile[cn][nn] * nscale);
  }
}

// ---------------- one-time bias folding: bq = (ln1_b.Wqkv)*[lc|1], b1f = b1 + ln2_b.W1,
// Wc1s = lnf_g (.) Wc1, bc1f = bc1 + lnf_b.Wc1 ----------------
__global__ __launch_bounds__(256) void k_bias(
    const float* __restrict__ Wq, const float* __restrict__ Wk, const float* __restrict__ Wv,
    const float* __restrict__ W1, const float* __restrict__ l1b, const float* __restrict__ l2b,
    const float* __restrict__ b1, const float* __restrict__ Wc1, const float* __restrict__ lnfg,
    const float* __restrict__ lnfb, const float* __restrict__ bc1,
    float* __restrict__ bq, float* __restrict__ b1f, float* __restrict__ Wc1s, float* __restrict__ bc1f) {
  __shared__ float red[4][64];
  int bid = blockIdx.x, t = threadIdx.x;
  if (bid < 64) {
    int l = bid >> 4, seg = bid & 15;
    int o = seg*64 + (t & 63), pp = t >> 6;
    float s = 0.f;
    if (o < 768) {
      const float* W = (o < 256 ? Wq : (o < 512 ? Wk : Wv)) + l*65536;
      int nn = o & 255, h = nn >> 5, d = nn & 31;
      const float* bv = l1b + l*256;
      for (int k = pp*64; k < pp*64+64; ++k) s = fmaf(bv[k], W[(h*256 + k)*32 + d], s);
    } else {
      const float* W = W1 + l*65536;
      int n = o - 768;
      const float* bv = l2b + l*256;
      for (int k = pp*64; k < pp*64+64; ++k) s = fmaf(bv[k], W[k*256 + n], s);
    }
    red[pp][t & 63] = s;
    __syncthreads();
    if (t < 64) {
      float tot = red[0][t]+red[1][t]+red[2][t]+red[3][t];
      int oo = seg*64 + t;
      if (oo < 768) bq[l*768 + oo] = tot * (oo < 256 ? LC : 1.f);
      else          b1f[l*256 + (oo-768)] = b1[l*256 + (oo-768)] + tot;
    }
  } else if (bid < 128) {
    int base = (bid-64)*2048;
    #pragma unroll
    for (int i=0;i<8;++i) {
      int idx = base + i*256 + t;
      Wc1s[idx] = Wc1[idx] * lnfg[idx >> 9];
    }
  } else {
    for (int u = t; u < 512; u += 256) {
      float s = bc1[u];
      for (int k=0;k<256;++k) s = fmaf(lnfb[k], Wc1[k*512+u], s);
      bc1f[u] = s;
    }
  }
}

// ---------------- embedding: fp32 residual stream ----------------
__global__ __launch_bounds__(256) void k_embed(const int* __restrict__ idx,
    const float* __restrict__ tok, const float* __restrict__ pos, float* __restrict__ x) {
  int i  = blockIdx.x*256 + threadIdx.x;      // over NTOK*CDIM/4
  int c4 = (i & 63) * 4;
  int bt = i >> 6;
  int t  = bt & (TDIM-1);
  float4 tv = *(const float4*)&tok[(size_t)idx[bt]*CDIM + c4];
  float4 pv = *(const float4*)&pos[(size_t)t*CDIM + c4];
  *(float4*)&x[(size_t)bt*CDIM + c4] =
      make_float4(tv.x+pv.x, tv.y+pv.y, tv.z+pv.z, tv.w+pv.w);
}

// ---------------- LDS-free MFMA GEMM, optional fused LN-standardization of A ----------------
// 1 wave/block, tile 32 x (NF*16). LNA: A is fp32 residual; block computes row mean/var
// (4 shuffles) then normalizes in-register (g/b already folded into Bt/bias).
template<int NF, bool LNA, bool BIAS, bool RELU, bool OUTBF16, bool ACCUM>
__global__ __launch_bounds__(64) void k_gemm3(const void* __restrict__ Av,
    const short* __restrict__ Bt, const float* __restrict__ bias, void* __restrict__ Cv,
    int outstride) {
  const int lane = threadIdx.x;
  const int q4 = lane >> 4, r = lane & 15;
  const int blockRow = blockIdx.x * 32;
  const int blockCol = blockIdx.y * (NF*16);
  const float* Af = (const float*)Av;
  const short* Ab = (const short*)Av;
  float4v acc[2][NF];
  #pragma unroll
  for (int i=0;i<2;++i)
    #pragma unroll
    for (int j=0;j<NF;++j) acc[i][j] = (float4v){0,0,0,0};
  float aS[2], cS[2];
  if (LNA) {
    #pragma unroll
    for (int rr=0; rr<2; ++rr) {
      const float* rp = Af + (size_t)(blockRow + rr*16 + r)*CDIM + q4*8;
      float s1 = 0.f, s2 = 0.f;
      #pragma unroll
      for (int k0=0;k0<8;++k0) {
        float4 va = *(const float4*)(rp + k0*32);
        float4 vb = *(const float4*)(rp + k0*32 + 4);
        s1 += ((va.x+va.y)+(va.z+va.w)) + ((vb.x+vb.y)+(vb.z+vb.w));
        s2 = fmaf(va.x,va.x, fmaf(va.y,va.y, fmaf(va.z,va.z, fmaf(va.w,va.w, s2))));
        s2 = fmaf(vb.x,vb.x, fmaf(vb.y,vb.y, fmaf(vb.z,vb.z, fmaf(vb.w,vb.w, s2))));
      }
      s1 += __shfl_xor(s1,16,64); s1 += __shfl_xor(s1,32,64);
      s2 += __shfl_xor(s2,16,64); s2 += __shfl_xor(s2,32,64);
      float mean = s1*(1.f/256.f);
      float inv  = rsqrtf(s2*(1.f/256.f) - mean*mean + 1e-5f);
      aS[rr] = inv; cS[rr] = -mean*inv;
    }
  }
  #pragma unroll
  for (int k0 = 0; k0 < 256; k0 += 32) {
    short8v a0, a1;
    if (LNA) {
      #pragma unroll
      for (int rr=0;rr<2;++rr) {
        const float* rp = Af + (size_t)(blockRow + rr*16 + r)*CDIM + k0 + q4*8;
        float4 va = *(const float4*)rp;
        float4 vb = *(const float4*)(rp+4);
        union { unsigned u[4]; short8v s; } pa;
        pa.u[0] = pkbf(fmaf(va.x,aS[rr],cS[rr]), fmaf(va.y,aS[rr],cS[rr]));
        pa.u[1] = pkbf(fmaf(va.z,aS[rr],cS[rr]), fmaf(va.w,aS[rr],cS[rr]));
        pa.u[2] = pkbf(fmaf(vb.x,aS[rr],cS[rr]), fmaf(vb.y,aS[rr],cS[rr]));
        pa.u[3] = pkbf(fmaf(vb.z,aS[rr],cS[rr]), fmaf(vb.w,aS[rr],cS[rr]));
        if (rr==0) a0 = pa.s; else a1 = pa.s;
      }
    } else {
      a0 = *(const short8v*)&Ab[(size_t)(blockRow +      r)*CDIM + k0 + q4*8];
      a1 = *(const short8v*)&Ab[(size_t)(blockRow + 16 + r)*CDIM + k0 + q4*8];
    }
    #pragma unroll
    for (int nf=0; nf<NF; ++nf) {
      short8v bf = *(const short8v*)&Bt[(size_t)(blockCol + nf*16 + r)*256 + k0 + q4*8];
      acc[0][nf] = mfma32(a0, bf, acc[0][nf]);
      acc[1][nf] = mfma32(a1, bf, acc[1][nf]);
    }
  }
  #pragma unroll
  for (int mf=0; mf<2; ++mf)
    #pragma unroll
    for (int nf=0; nf<NF; ++nf) {
      int col = blockCol + nf*16 + r;
      float bb = BIAS ? bias[col] : 0.f;
      #pragma unroll
      for (int reg=0; reg<4; ++reg) {
        int row = blockRow + mf*16 + q4*4 + reg;
        float v = acc[mf][nf][reg] + bb;
        if (RELU) v = fmaxf(v, 0.f);
        size_t oi = (size_t)row*outstride + col;
        if (ACCUM)        ((float*)Cv)[oi] += v;
        else if (OUTBF16) ((short*)Cv)[oi] = f2bs(v);
        else              ((float*)Cv)[oi] = v;
      }
    }
}

// ---------------- MFMA flash attention: double-buffered staging, 1 barrier/tile ----------------
// grid (16,H,B), 512 thr; waves 0-3 stage K (b128), waves 4-7 stage V (b32 key-pairs).
// Q pre-scaled by LC at prep, so score -> exp2 directly.
#define KS_STRIDE 40
#define VT_STRIDE 76
__global__ __launch_bounds__(512) void k_attn5(const short* __restrict__ qkv,
    short* __restrict__ O) {
  __shared__ __align__(16) short Ks[2][64*KS_STRIDE];
  __shared__ __align__(16) short Vt[2][32*VT_STRIDE];
  const int tid = threadIdx.x;
  const int w = tid >> 6, lane = tid & 63;
  const int q4 = lane >> 4, r = lane & 15;
  const int b = blockIdx.z, h = blockIdx.y;
  const int rowbase = blockIdx.x*128 + w*16;
  short8v Qf = *(const short8v*)&qkv[((size_t)(b*TDIM + rowbase + r))*QSTR + h*HSZ + q4*8];
  float4v o0 = {0,0,0,0}, o1 = {0,0,0,0};
  float l0 = 0.f;
  const bool isV = tid >= 256;
  const int t2 = tid & 255;
  const int skey = t2 >> 2, kd0 = (t2 & 3)*8;   // K staging
  const int kp = t2 & 31, dg = t2 >> 5;         // V staging (key pairs)
  const short* kvbase = qkv + (size_t)b*TDIM*QSTR + h*HSZ;
  short8v kv; short4v vv0, vv1;
  if (isV) {
    vv0 = *(const short4v*)&kvbase[(size_t)(2*kp)*QSTR   + 2*CDIM + dg*4];
    vv1 = *(const short4v*)&kvbase[(size_t)(2*kp+1)*QSTR + 2*CDIM + dg*4];
  } else {
    kv = *(const short8v*)&kvbase[(size_t)skey*QSTR + CDIM + kd0];
  }
  int p = 0;
  for (int s0 = 0; s0 < TDIM; s0 += 64, p ^= 1) {
    if (isV) {
      union { short4v s; unsigned u[2]; } a, c;
      a.s = vv0; c.s = vv1;
      *(unsigned*)&Vt[p][(dg*4+0)*VT_STRIDE + 2*kp] = __builtin_amdgcn_perm(c.u[0], a.u[0], 0x05040100u);
      *(unsigned*)&Vt[p][(dg*4+1)*VT_STRIDE + 2*kp] = __builtin_amdgcn_perm(c.u[0], a.u[0], 0x07060302u);
      *(unsigned*)&Vt[p][(dg*4+2)*VT_STRIDE + 2*kp] = __builtin_amdgcn_perm(c.u[1], a.u[1], 0x05040100u);
      *(unsigned*)&Vt[p][(dg*4+3)*VT_STRIDE + 2*kp] = __builtin_amdgcn_perm(c.u[1], a.u[1], 0x07060302u);
    } else {
      *(short8v*)&Ks[p][skey*KS_STRIDE + kd0] = kv;
    }
    if (s0 + 64 < TDIM) {                        // prefetch next tile before barrier
      const short* nb = kvbase + (size_t)(s0+64)*QSTR;
      if (isV) {
        vv0 = *(const short4v*)&nb[(size_t)(2*kp)*QSTR   + 2*CDIM + dg*4];
        vv1 = *(const short4v*)&nb[(size_t)(2*kp+1)*QSTR + 2*CDIM + dg*4];
      } else {
        kv = *(const short8v*)&nb[(size_t)skey*QSTR + CDIM + kd0];
      }
    }
    __syncthreads();
    #pragma unroll
    for (int ks = 0; ks < 4; ++ks) {
      short8v Kf = *(const short8v*)&Ks[p][(ks*16 + r)*KS_STRIDE + q4*8];
      float4v sv = mfma32(Kf, Qf, (float4v){0,0,0,0});
      short4v Vf0 = *(const short4v*)&Vt[p][r*VT_STRIDE + ks*16 + q4*4];
      short4v Vf1 = *(const short4v*)&Vt[p][(16+r)*VT_STRIDE + ks*16 + q4*4];
      float p0 = fexp2(sv[0]), p1 = fexp2(sv[1]);
      float p2 = fexp2(sv[2]), p3 = fexp2(sv[3]);
      l0 += (p0+p1) + (p2+p3);
      union { unsigned u[2]; short4v s; } P;
      P.u[0] = pkbf(p0, p1); P.u[1] = pkbf(p2, p3);
      o0 = mfma16(P.s, Vf0, o0);
      o1 = mfma16(P.s, Vf1, o1);
    }
  }
  l0 += __shfl_xor(l0, 16, 64); l0 += __shfl_xor(l0, 32, 64);
  #pragma unroll
  for (int reg=0; reg<4; ++reg) {
    int qrow = q4*4 + reg;
    float i0 = 1.f / __shfl(l0, qrow, 64);
    short* op = O + ((size_t)(b*TDIM + rowbase + qrow))*CDIM + h*HSZ;
    op[r]    = f2bs(o0[reg]*i0);
    op[16+r] = f2bs(o1[reg]*i0);
  }
}

// ---------------- fused final-LN + mean-pool (g/b folded into Wc1s/bc1f) ----------------
__global__ __launch_bounds__(256) void k_poolln(const float* __restrict__ X, float* __restrict__ part) {
  __shared__ float red[4][256];
  int b = blockIdx.x >> 3, chunk = blockIdx.x & 7;
  int wv = threadIdx.x >> 6, lane = threadIdx.x & 63;
  int base = b*TDIM + chunk*256 + wv*64;
  float a0=0,a1=0,a2=0,a3=0;
  for (int rr=0; rr<64; ++rr) {
    float4 v = *(const float4*)&X[(size_t)(base+rr)*CDIM + lane*4];
    float s1 = (v.x+v.y)+(v.z+v.w);
    float s2 = fmaf(v.x,v.x, fmaf(v.y,v.y, fmaf(v.z,v.z, v.w*v.w)));
    #pragma unroll
    for (int off=32; off>0; off>>=1) { s1 += __shfl_xor(s1,off,64); s2 += __shfl_xor(s2,off,64); }
    float mean = s1*(1.f/256.f);
    float inv  = rsqrtf(s2*(1.f/256.f) - mean*mean + 1e-5f);
    a0 = fmaf(v.x-mean, inv, a0); a1 = fmaf(v.y-mean, inv, a1);
    a2 = fmaf(v.z-mean, inv, a2); a3 = fmaf(v.w-mean, inv, a3);
  }
  red[wv][lane*4+0]=a0; red[wv][lane*4+1]=a1; red[wv][lane*4+2]=a2; red[wv][lane*4+3]=a3;
  __syncthreads();
  int c = threadIdx.x;
  part[blockIdx.x*256 + c] = (red[0][c]+red[1][c]+red[2][c]+red[3][c]) * (1.f/2048.f);
}

// ---------------- classifier stage 1: combine partials + fc1 + relu ----------------
__global__ __launch_bounds__(256) void k_cls1(const float* __restrict__ part,
    const float* __restrict__ Wc1s, const float* __restrict__ bc1f, float* __restrict__ hid) {
  __shared__ float se[256];
  const int b = blockIdx.y;
  const int u = blockIdx.x*256 + threadIdx.x;
  const int c = threadIdx.x;
  float s = 0.f;
  #pragma unroll
  for (int ch=0; ch<8; ++ch) s += part[(b*8+ch)*256 + c];
  se[c] = s;
  __syncthreads();
  float acc = bc1f[u];
  #pragma unroll 16
  for (int c2=0; c2<256; ++c2) acc = fmaf(se[c2], Wc1s[c2*512 + u], acc);
  hid[b*512 + u] = fmaxf(acc, 0.f);
}

// ---------------- classifier stage 2: fc2 + softmax ----------------
__global__ __launch_bounds__(256) void k_cls2(const float* __restrict__ hid,
    const float* __restrict__ Wc2, const float* __restrict__ bc2, float* __restrict__ out) {
  __shared__ float red[160];
  __shared__ float sl[40];
  const int t = threadIdx.x;
  if (t < 160) {
    int o = t >> 2, pp = t & 3;
    int b = o / 10, j = o - b*10;
    const float* hp = hid + b*512 + pp*128;
    float s = 0.f;
    #pragma unroll 8
    for (int u=0; u<128; ++u) s = fmaf(hp[u], Wc2[(pp*128+u)*10 + j], s);
    red[t] = s;
  }
  __syncthreads();
  if (t < 40) sl[t] = (red[t*4]+red[t*4+1]) + (red[t*4+2]+red[t*4+3]) + bc2[t%10];
  __syncthreads();
  if (t < 4) {
    float mx = -1e30f;
    for (int j=0;j<10;++j) mx = fmaxf(mx, sl[t*10+j]);
    float e[10], sum = 0.f;
    for (int j=0;j<10;++j) { e[j] = __expf(sl[t*10+j]-mx); sum += e[j]; }
    float inv = 1.f/sum;
    for (int j=0;j<10;++j) out[t*10+j] = e[j]*inv;
  }
}

extern "C" void kernel_launch(void* const* d_in, const int* in_sizes, int n_in,
                              void* d_out, int out_size, void* d_ws, size_t ws_size,
                              hipStream_t stream) {
  const int*   idx = (const int*)d_in[0];
  const float* tok = (const float*)d_in[1];
  const float* pos = (const float*)d_in[2];
  const float* Wq  = (const float*)d_in[3];
  const float* Wk  = (const float*)d_in[4];
  const float* Wv  = (const float*)d_in[5];
  const float* Wp  = (const float*)d_in[6];
  const float* bp  = (const float*)d_in[7];
  const float* l1g = (const float*)d_in[8];
  const float* l1b = (const float*)d_in[9];
  const float* l2g = (const float*)d_in[10];
  const float* l2b = (const float*)d_in[11];
  const float* W1  = (const float*)d_in[12];
  const float* b1  = (const float*)d_in[13];
  const float* W2  = (const float*)d_in[14];
  const float* b2  = (const float*)d_in[15];
  const float* lfg = (const float*)d_in[16];
  const float* lfb = (const float*)d_in[17];
  const float* Wc1 = (const float*)d_in[18];
  const float* bc1 = (const float*)d_in[19];
  const float* Wc2 = (const float*)d_in[20];
  const float* bc2 = (const float*)d_in[21];

  char* p = (char*)d_ws;
  float* xb   = (float*)p;              p += (size_t)BUF*4;        // fp32 residual (8 MB)
  short* hb   = (short*)p;              p += (size_t)BUF*2;        // bf16 attn out (4 MB)
  short* qkvb = (short*)p;              p += (size_t)NTOK*QSTR*2;  // bf16 fused QKV (12 MB)
  float* part = (float*)p;              p += 32*256*4;
  float* hid  = (float*)p;              p += 4*512*4;
  short* wqkvT = (short*)p;             p += (size_t)LNUM*QSTR*256*2;
  short* wpT   = (short*)p;             p += (size_t)LNUM*65536*2;
  short* w1T   = (short*)p;             p += (size_t)LNUM*65536*2;
  short* w2T   = (short*)p;             p += (size_t)LNUM*65536*2;
  float* bq    = (float*)p;             p += (size_t)LNUM*768*4;
  float* b1f   = (float*)p;             p += (size_t)LNUM*256*4;
  float* Wc1s  = (float*)p;             p += (size_t)256*512*4;
  float* bc1f  = (float*)p;             p += 512*4;
  short* fh    = qkvb;                  // FFN hidden reuses qkv buffer

  k_prep<<<384, 256, 0, stream>>>(Wq, Wk, Wv, Wp, W1, W2, l1g, l2g, wqkvT, wpT, w1T, w2T);
  k_bias<<<129, 256, 0, stream>>>(Wq, Wk, Wv, W1, l1b, l2b, b1, Wc1, lfg, lfb, bc1,
                                  bq, b1f, Wc1s, bc1f);
  k_embed<<<NTOK*CDIM/1024, 256, 0, stream>>>(idx, tok, pos, xb);
  for (int l = 0; l < LNUM; ++l) {
    k_gemm3<4,true,true,false,true,false><<<dim3(256,12), 64, 0, stream>>>(
        xb, wqkvT + (size_t)l*QSTR*256, bq + l*768, qkvb, QSTR);
    k_attn5<<<dim3(16, HDIM, BDIM), 512, 0, stream>>>(qkvb, hb);
    k_gemm3<2,false,true,false,false,true><<<dim3(256,8), 64, 0, stream>>>(
        hb, wpT + (size_t)l*65536, bp + l*CDIM, xb, CDIM);
    k_gemm3<2,true,true,true,true,false><<<dim3(256,8), 64, 0, stream>>>(
        xb, w1T + (size_t)l*65536, b1f + l*CDIM, fh, CDIM);
    k_gemm3<2,false,true,false,false,true><<<dim3(256,8), 64, 0, stream>>>(
        fh, w2T + (size_t)l*65536, b2 + l*CDIM, xb, CDIM);
  }
  k_poolln<<<32, 256, 0, stream>>>(xb, part);
  k_cls1<<<dim3(2,4), 256, 0, stream>>>(part, Wc1s, bc1f, hid);
  k_cls2<<<1, 256, 0, stream>>>(hid, Wc2, bc2, (float*)d_out);
}

// Round 10
// 602.368 us; speedup vs baseline: 1.0613x; 1.0613x over previous
//
#include <hip/hip_runtime.h>
#include <hip/hip_bf16.h>

#define NTOK 8192      // B*T
#define CDIM 256
#define TDIM 2048
#define BDIM 4
#define HDIM 8
#define HSZ  32
#define LNUM 4
#define BUF  (NTOK*CDIM)
#define QSTR 768       // fused qkv row stride
#define LC   0.0901684400056f   // 2^-4 * log2(e), folded into Wq/bq

typedef __attribute__((ext_vector_type(8))) short short8v;
typedef __attribute__((ext_vector_type(4))) short short4v;
typedef __attribute__((ext_vector_type(4))) float float4v;

static __device__ __forceinline__ short f2bs(float f){
  union { float f; unsigned u; } x; x.f = f;
  unsigned r = x.u + 0x7FFFu + ((x.u >> 16) & 1u);
  return (short)(r >> 16);
}
// pack two fp32 -> bf16x2 (RNE); low = a, high = b
static __device__ __forceinline__ unsigned pkbf(float a, float b){
  union { float f; unsigned u; } x, y; x.f = a; y.f = b;
  unsigned ra = x.u + 0x7FFFu + ((x.u >> 16) & 1u);
  unsigned rb = y.u + 0x7FFFu + ((y.u >> 16) & 1u);
  return __builtin_amdgcn_perm(rb, ra, 0x07060302u);
}
#if __has_builtin(__builtin_amdgcn_exp2f)
static __device__ __forceinline__ float fexp2(float x){ return __builtin_amdgcn_exp2f(x); }
#else
static __device__ __forceinline__ float fexp2(float x){ return __expf(x*0.6931471805599453f); }
#endif

#if __has_builtin(__builtin_amdgcn_mfma_f32_16x16x16bf16_1k)
static __device__ __forceinline__ float4v mfma16(short4v a, short4v b, float4v c){
  return __builtin_amdgcn_mfma_f32_16x16x16bf16_1k(a, b, c, 0, 0, 0);
}
#else
static __device__ __forceinline__ float4v mfma16(short4v a, short4v b, float4v c){
  float4v d;
  asm volatile("v_mfma_f32_16x16x16_bf16 %0, %1, %2, %3\n\ts_nop 7\n\ts_nop 7"
               : "=v"(d) : "v"(a), "v"(b), "v"(c));
  return d;
}
#endif
static __device__ __forceinline__ float4v mfma32(short8v a, short8v b, float4v c){
  return __builtin_amdgcn_mfma_f32_16x16x32_bf16(a, b, c, 0, 0, 0);
}

// ---------------- weight prep: transpose to bf16 [N][K], folding LN gains + softmax scale ----
__global__ __launch_bounds__(256) void k_prep(
    const float* __restrict__ Wq, const float* __restrict__ Wk, const float* __restrict__ Wv,
    const float* __restrict__ Wp, const float* __restrict__ W1, const float* __restrict__ W2,
    const float* __restrict__ l1g, const float* __restrict__ l2g,
    short* __restrict__ qkvT, short* __restrict__ wpT, short* __restrict__ w1T, short* __restrict__ w2T) {
  __shared__ float tile[64][65];
  const int tid = threadIdx.x;
  int id = blockIdx.x;
  int l = id / 96, rr = id % 96;
  const float* src; short* dst; int n0, k0; bool qkvmode; int gsel; float nscale = 1.f;
  if (rr < 48) {
    int tn = rr >> 2, tk = rr & 3;
    n0 = tn*64; k0 = tk*64;
    const float* b3 = (n0 < 256) ? Wq : (n0 < 512 ? Wk : Wv);
    src = b3 + l*65536;
    dst = qkvT + (size_t)l*QSTR*256;
    qkvmode = true; gsel = 1;
    if (n0 < 256) nscale = LC;              // fold softmax scale into Q weights
  } else {
    int r2 = rr - 48;
    int mat = r2 >> 4, t = r2 & 15;
    int tn = t >> 2, tk = t & 3;
    n0 = tn*64; k0 = tk*64;
    const float* b3 = (mat == 0) ? Wp : (mat == 1 ? W1 : W2);
    src = b3 + l*65536;
    dst = (mat == 0 ? wpT : (mat == 1 ? w1T : w2T)) + l*65536;
    qkvmode = false; gsel = (mat == 1) ? 2 : 0;
  }
  const int cn = tid & 63, rk = tid >> 6;
  #pragma unroll
  for (int i = 0; i < 16; ++i) {
    int kk = rk + i*4;
    int n = n0 + cn, k = k0 + kk;
    float v;
    if (qkvmode) { int nn = n & 255; v = src[((nn>>5)*256 + k)*32 + (nn & 31)]; }
    else         { v = src[k*256 + n]; }
    if (gsel == 1)      v *= l1g[l*256 + k];
    else if (gsel == 2) v *= l2g[l*256 + k];
    tile[kk][cn] = v;
  }
  __syncthreads();
  #pragma unroll
  for (int i = 0; i < 16; ++i) {
    int nn = rk + i*4;
    dst[(size_t)(n0 + nn)*256 + k0 + cn] = f2bs(tile[cn][nn] * nscale);
  }
}

// ---------------- one-time bias folding ----------------
__global__ __launch_bounds__(256) void k_bias(
    const float* __restrict__ Wq, const float* __restrict__ Wk, const float* __restrict__ Wv,
    const float* __restrict__ W1, const float* __restrict__ l1b, const float* __restrict__ l2b,
    const float* __restrict__ b1, const float* __restrict__ Wc1, const float* __restrict__ lnfg,
    const float* __restrict__ lnfb, const float* __restrict__ bc1,
    float* __restrict__ bq, float* __restrict__ b1f, float* __restrict__ Wc1s, float* __restrict__ bc1f) {
  __shared__ float red[4][64];
  int bid = blockIdx.x, t = threadIdx.x;
  if (bid < 64) {
    int l = bid >> 4, seg = bid & 15;
    int o = seg*64 + (t & 63), pp = t >> 6;
    float s = 0.f;
    if (o < 768) {
      const float* W = (o < 256 ? Wq : (o < 512 ? Wk : Wv)) + l*65536;
      int nn = o & 255, h = nn >> 5, d = nn & 31;
      const float* bv = l1b + l*256;
      for (int k = pp*64; k < pp*64+64; ++k) s = fmaf(bv[k], W[(h*256 + k)*32 + d], s);
    } else {
      const float* W = W1 + l*65536;
      int n = o - 768;
      const float* bv = l2b + l*256;
      for (int k = pp*64; k < pp*64+64; ++k) s = fmaf(bv[k], W[k*256 + n], s);
    }
    red[pp][t & 63] = s;
    __syncthreads();
    if (t < 64) {
      float tot = red[0][t]+red[1][t]+red[2][t]+red[3][t];
      int oo = seg*64 + t;
      if (oo < 768) bq[l*768 + oo] = tot * (oo < 256 ? LC : 1.f);
      else          b1f[l*256 + (oo-768)] = b1[l*256 + (oo-768)] + tot;
    }
  } else if (bid < 128) {
    int base = (bid-64)*2048;
    #pragma unroll
    for (int i=0;i<8;++i) {
      int idx = base + i*256 + t;
      Wc1s[idx] = Wc1[idx] * lnfg[idx >> 9];
    }
  } else {
    for (int u = t; u < 512; u += 256) {
      float s = bc1[u];
      for (int k=0;k<256;++k) s = fmaf(lnfb[k], Wc1[k*512+u], s);
      bc1f[u] = s;
    }
  }
}

// ---------------- embedding: fp32 residual stream ----------------
__global__ __launch_bounds__(256) void k_embed(const int* __restrict__ idx,
    const float* __restrict__ tok, const float* __restrict__ pos, float* __restrict__ x) {
  int i  = blockIdx.x*256 + threadIdx.x;      // over NTOK*CDIM/4
  int c4 = (i & 63) * 4;
  int bt = i >> 6;
  int t  = bt & (TDIM-1);
  float4 tv = *(const float4*)&tok[(size_t)idx[bt]*CDIM + c4];
  float4 pv = *(const float4*)&pos[(size_t)t*CDIM + c4];
  *(float4*)&x[(size_t)bt*CDIM + c4] =
      make_float4(tv.x+pv.x, tv.y+pv.y, tv.z+pv.z, tv.w+pv.w);
}

// ---------------- layernorm (standardize only; g/b folded into weights): wave per row --------
__global__ __launch_bounds__(256) void k_ln(const float* __restrict__ X, short* __restrict__ Y) {
  const int lane = threadIdx.x & 63;
  const int row = blockIdx.x*4 + (threadIdx.x >> 6);
  float4 v = *(const float4*)&X[(size_t)row*CDIM + lane*4];
  float s1 = (v.x+v.y) + (v.z+v.w);
  float s2 = fmaf(v.x,v.x, fmaf(v.y,v.y, fmaf(v.z,v.z, v.w*v.w)));
  #pragma unroll
  for (int off=32; off>0; off>>=1) { s1 += __shfl_xor(s1, off, 64); s2 += __shfl_xor(s2, off, 64); }
  float mean = s1*(1.f/CDIM);
  float var  = s2*(1.f/CDIM) - mean*mean;
  float inv  = rsqrtf(var + 1e-5f);
  float cc = -mean*inv;
  union { unsigned u[2]; short4v s; } o;
  o.u[0] = pkbf(fmaf(v.x,inv,cc), fmaf(v.y,inv,cc));
  o.u[1] = pkbf(fmaf(v.z,inv,cc), fmaf(v.w,inv,cc));
  *(short4v*)&Y[(size_t)row*CDIM + lane*4] = o.s;
}

// ---------------- LDS-free MFMA GEMM: C[8192,NF*16*gridy] = A(bf16) x Bt[N][256](bf16) --------
// 1 wave/block, wave tile 32 x (NF*16). Frag layouts verified rounds 5/6.
template<int NF, bool BIAS, bool RELU, bool OUTBF16, bool ACCUM>
__global__ __launch_bounds__(64) void k_gemm3(const short* __restrict__ A,
    const short* __restrict__ Bt, const float* __restrict__ bias, void* __restrict__ Cv,
    int outstride) {
  const int lane = threadIdx.x;
  const int q4 = lane >> 4, r = lane & 15;
  const int blockRow = blockIdx.x * 32;
  const int blockCol = blockIdx.y * (NF*16);
  float4v acc[2][NF];
  #pragma unroll
  for (int i=0;i<2;++i)
    #pragma unroll
    for (int j=0;j<NF;++j) acc[i][j] = (float4v){0,0,0,0};
  #pragma unroll
  for (int k0 = 0; k0 < 256; k0 += 32) {
    short8v a0 = *(const short8v*)&A[(size_t)(blockRow +      r)*CDIM + k0 + q4*8];
    short8v a1 = *(const short8v*)&A[(size_t)(blockRow + 16 + r)*CDIM + k0 + q4*8];
    #pragma unroll
    for (int nf=0; nf<NF; ++nf) {
      short8v bf = *(const short8v*)&Bt[(size_t)(blockCol + nf*16 + r)*256 + k0 + q4*8];
      acc[0][nf] = mfma32(a0, bf, acc[0][nf]);
      acc[1][nf] = mfma32(a1, bf, acc[1][nf]);
    }
  }
  #pragma unroll
  for (int mf=0; mf<2; ++mf)
    #pragma unroll
    for (int nf=0; nf<NF; ++nf) {
      int col = blockCol + nf*16 + r;
      float bb = BIAS ? bias[col] : 0.f;
      #pragma unroll
      for (int reg=0; reg<4; ++reg) {
        int row = blockRow + mf*16 + q4*4 + reg;
        float v = acc[mf][nf][reg] + bb;
        if (RELU) v = fmaxf(v, 0.f);
        size_t oi = (size_t)row*outstride + col;
        if (ACCUM)        ((float*)Cv)[oi] += v;
        else if (OUTBF16) ((short*)Cv)[oi] = f2bs(v);
        else              ((float*)Cv)[oi] = v;
      }
    }
}

// ---------------- MFMA flash attention: double-buffered staging, 1 barrier/tile ----------------
#define KS_STRIDE 40
#define VT_STRIDE 76
__global__ __launch_bounds__(512) void k_attn5(const short* __restrict__ qkv,
    short* __restrict__ O) {
  __shared__ __align__(16) short Ks[2][64*KS_STRIDE];
  __shared__ __align__(16) short Vt[2][32*VT_STRIDE];
  const int tid = threadIdx.x;
  const int w = tid >> 6, lane = tid & 63;
  const int q4 = lane >> 4, r = lane & 15;
  const int b = blockIdx.z, h = blockIdx.y;
  const int rowbase = blockIdx.x*128 + w*16;
  short8v Qf = *(const short8v*)&qkv[((size_t)(b*TDIM + rowbase + r))*QSTR + h*HSZ + q4*8];
  float4v o0 = {0,0,0,0}, o1 = {0,0,0,0};
  float l0 = 0.f;
  const bool isV = tid >= 256;
  const int t2 = tid & 255;
  const int skey = t2 >> 2, kd0 = (t2 & 3)*8;   // K staging
  const int kp = t2 & 31, dg = t2 >> 5;         // V staging (key pairs)
  const short* kvbase = qkv + (size_t)b*TDIM*QSTR + h*HSZ;
  short8v kv; short4v vv0, vv1;
  if (isV) {
    vv0 = *(const short4v*)&kvbase[(size_t)(2*kp)*QSTR   + 2*CDIM + dg*4];
    vv1 = *(const short4v*)&kvbase[(size_t)(2*kp+1)*QSTR + 2*CDIM + dg*4];
  } else {
    kv = *(const short8v*)&kvbase[(size_t)skey*QSTR + CDIM + kd0];
  }
  int p = 0;
  for (int s0 = 0; s0 < TDIM; s0 += 64, p ^= 1) {
    if (isV) {
      union { short4v s; unsigned u[2]; } a, c;
      a.s = vv0; c.s = vv1;
      *(unsigned*)&Vt[p][(dg*4+0)*VT_STRIDE + 2*kp] = __builtin_amdgcn_perm(c.u[0], a.u[0], 0x05040100u);
      *(unsigned*)&Vt[p][(dg*4+1)*VT_STRIDE + 2*kp] = __builtin_amdgcn_perm(c.u[0], a.u[0], 0x07060302u);
      *(unsigned*)&Vt[p][(dg*4+2)*VT_STRIDE + 2*kp] = __builtin_amdgcn_perm(c.u[1], a.u[1], 0x05040100u);
      *(unsigned*)&Vt[p][(dg*4+3)*VT_STRIDE + 2*kp] = __builtin_amdgcn_perm(c.u[1], a.u[1], 0x07060302u);
    } else {
      *(short8v*)&Ks[p][skey*KS_STRIDE + kd0] = kv;
    }
    if (s0 + 64 < TDIM) {                        // prefetch next tile before barrier
      const short* nb = kvbase + (size_t)(s0+64)*QSTR;
      if (isV) {
        vv0 = *(const short4v*)&nb[(size_t)(2*kp)*QSTR   + 2*CDIM + dg*4];
        vv1 = *(const short4v*)&nb[(size_t)(2*kp+1)*QSTR + 2*CDIM + dg*4];
      } else {
        kv = *(const short8v*)&nb[(size_t)skey*QSTR + CDIM + kd0];
      }
    }
    __syncthreads();
    #pragma unroll
    for (int ks = 0; ks < 4; ++ks) {
      short8v Kf = *(const short8v*)&Ks[p][(ks*16 + r)*KS_STRIDE + q4*8];
      float4v sv = mfma32(Kf, Qf, (float4v){0,0,0,0});
      short4v Vf0 = *(const short4v*)&Vt[p][r*VT_STRIDE + ks*16 + q4*4];
      short4v Vf1 = *(const short4v*)&Vt[p][(16+r)*VT_STRIDE + ks*16 + q4*4];
      float p0 = fexp2(sv[0]), p1 = fexp2(sv[1]);
      float p2 = fexp2(sv[2]), p3 = fexp2(sv[3]);
      l0 += (p0+p1) + (p2+p3);
      union { unsigned u[2]; short4v s; } P;
      P.u[0] = pkbf(p0, p1); P.u[1] = pkbf(p2, p3);
      o0 = mfma16(P.s, Vf0, o0);
      o1 = mfma16(P.s, Vf1, o1);
    }
  }
  l0 += __shfl_xor(l0, 16, 64); l0 += __shfl_xor(l0, 32, 64);
  #pragma unroll
  for (int reg=0; reg<4; ++reg) {
    int qrow = q4*4 + reg;
    float i0 = 1.f / __shfl(l0, qrow, 64);
    short* op = O + ((size_t)(b*TDIM + rowbase + qrow))*CDIM + h*HSZ;
    op[r]    = f2bs(o0[reg]*i0);
    op[16+r] = f2bs(o1[reg]*i0);
  }
}

// ---------------- fused final-LN + mean-pool (g/b folded into Wc1s/bc1f) ----------------
__global__ __launch_bounds__(256) void k_poolln(const float* __restrict__ X, float* __restrict__ part) {
  __shared__ float red[4][256];
  int b = blockIdx.x >> 3, chunk = blockIdx.x & 7;
  int wv = threadIdx.x >> 6, lane = threadIdx.x & 63;
  int base = b*TDIM + chunk*256 + wv*64;
  float a0=0,a1=0,a2=0,a3=0;
  for (int rr=0; rr<64; ++rr) {
    float4 v = *(const float4*)&X[(size_t)(base+rr)*CDIM + lane*4];
    float s1 = (v.x+v.y)+(v.z+v.w);
    float s2 = fmaf(v.x,v.x, fmaf(v.y,v.y, fmaf(v.z,v.z, v.w*v.w)));
    #pragma unroll
    for (int off=32; off>0; off>>=1) { s1 += __shfl_xor(s1,off,64); s2 += __shfl_xor(s2,off,64); }
    float mean = s1*(1.f/256.f);
    float inv  = rsqrtf(s2*(1.f/256.f) - mean*mean + 1e-5f);
    a0 = fmaf(v.x-mean, inv, a0); a1 = fmaf(v.y-mean, inv, a1);
    a2 = fmaf(v.z-mean, inv, a2); a3 = fmaf(v.w-mean, inv, a3);
  }
  red[wv][lane*4+0]=a0; red[wv][lane*4+1]=a1; red[wv][lane*4+2]=a2; red[wv][lane*4+3]=a3;
  __syncthreads();
  int c = threadIdx.x;
  part[blockIdx.x*256 + c] = (red[0][c]+red[1][c]+red[2][c]+red[3][c]) * (1.f/2048.f);
}

// ---------------- classifier stage 1: combine partials + fc1 + relu ----------------
__global__ __launch_bounds__(256) void k_cls1(const float* __restrict__ part,
    const float* __restrict__ Wc1s, const float* __restrict__ bc1f, float* __restrict__ hid) {
  __shared__ float se[256];
  const int b = blockIdx.y;
  const int u = blockIdx.x*256 + threadIdx.x;
  const int c = threadIdx.x;
  float s = 0.f;
  #pragma unroll
  for (int ch=0; ch<8; ++ch) s += part[(b*8+ch)*256 + c];
  se[c] = s;
  __syncthreads();
  float acc = bc1f[u];
  #pragma unroll 16
  for (int c2=0; c2<256; ++c2) acc = fmaf(se[c2], Wc1s[c2*512 + u], acc);
  hid[b*512 + u] = fmaxf(acc, 0.f);
}

// ---------------- classifier stage 2: fc2 + softmax ----------------
__global__ __launch_bounds__(256) void k_cls2(const float* __restrict__ hid,
    const float* __restrict__ Wc2, const float* __restrict__ bc2, float* __restrict__ out) {
  __shared__ float red[160];
  __shared__ float sl[40];
  const int t = threadIdx.x;
  if (t < 160) {
    int o = t >> 2, pp = t & 3;
    int b = o / 10, j = o - b*10;
    const float* hp = hid + b*512 + pp*128;
    float s = 0.f;
    #pragma unroll 8
    for (int u=0; u<128; ++u) s = fmaf(hp[u], Wc2[(pp*128+u)*10 + j], s);
    red[t] = s;
  }
  __syncthreads();
  if (t < 40) sl[t] = (red[t*4]+red[t*4+1]) + (red[t*4+2]+red[t*4+3]) + bc2[t%10];
  __syncthreads();
  if (t < 4) {
    float mx = -1e30f;
    for (int j=0;j<10;++j) mx = fmaxf(mx, sl[t*10+j]);
    float e[10], sum = 0.f;
    for (int j=0;j<10;++j) { e[j] = __expf(sl[t*10+j]-mx); sum += e[j]; }
    float inv = 1.f/sum;
    for (int j=0;j<10;++j) out[t*10+j] = e[j]*inv;
  }
}

extern "C" void kernel_launch(void* const* d_in, const int* in_sizes, int n_in,
                              void* d_out, int out_size, void* d_ws, size_t ws_size,
                              hipStream_t stream) {
  const int*   idx = (const int*)d_in[0];
  const float* tok = (const float*)d_in[1];
  const float* pos = (const float*)d_in[2];
  const float* Wq  = (const float*)d_in[3];
  const float* Wk  = (const float*)d_in[4];
  const float* Wv  = (const float*)d_in[5];
  const float* Wp  = (const float*)d_in[6];
  const float* bp  = (const float*)d_in[7];
  const float* l1g = (const float*)d_in[8];
  const float* l1b = (const float*)d_in[9];
  const float* l2g = (const float*)d_in[10];
  const float* l2b = (const float*)d_in[11];
  const float* W1  = (const float*)d_in[12];
  const float* b1  = (const float*)d_in[13];
  const float* W2  = (const float*)d_in[14];
  const float* b2  = (const float*)d_in[15];
  const float* lfg = (const float*)d_in[16];
  const float* lfb = (const float*)d_in[17];
  const float* Wc1 = (const float*)d_in[18];
  const float* bc1 = (const float*)d_in[19];
  const float* Wc2 = (const float*)d_in[20];
  const float* bc2 = (const float*)d_in[21];

  char* p = (char*)d_ws;
  float* xb   = (float*)p;              p += (size_t)BUF*4;        // fp32 residual (8 MB)
  short* hb   = (short*)p;              p += (size_t)BUF*2;        // bf16 LN/attn out (4 MB)
  short* qkvb = (short*)p;              p += (size_t)NTOK*QSTR*2;  // bf16 fused QKV (12 MB)
  float* part = (float*)p;              p += 32*256*4;
  float* hid  = (float*)p;              p += 4*512*4;
  short* wqkvT = (short*)p;             p += (size_t)LNUM*QSTR*256*2;
  short* wpT   = (short*)p;             p += (size_t)LNUM*65536*2;
  short* w1T   = (short*)p;             p += (size_t)LNUM*65536*2;
  short* w2T   = (short*)p;             p += (size_t)LNUM*65536*2;
  float* bq    = (float*)p;             p += (size_t)LNUM*768*4;
  float* b1f   = (float*)p;             p += (size_t)LNUM*256*4;
  float* Wc1s  = (float*)p;             p += (size_t)256*512*4;
  float* bc1f  = (float*)p;             p += 512*4;
  short* fh    = qkvb;                  // FFN hidden reuses qkv buffer

  k_prep<<<384, 256, 0, stream>>>(Wq, Wk, Wv, Wp, W1, W2, l1g, l2g, wqkvT, wpT, w1T, w2T);
  k_bias<<<129, 256, 0, stream>>>(Wq, Wk, Wv, W1, l1b, l2b, b1, Wc1, lfg, lfb, bc1,
                                  bq, b1f, Wc1s, bc1f);
  k_embed<<<NTOK*CDIM/1024, 256, 0, stream>>>(idx, tok, pos, xb);
  for (int l = 0; l < LNUM; ++l) {
    k_ln<<<NTOK/4, 256, 0, stream>>>(xb, hb);
    k_gemm3<4,true,false,true,false><<<dim3(256,12), 64, 0, stream>>>(
        hb, wqkvT + (size_t)l*QSTR*256, bq + l*768, qkvb, QSTR);
    k_attn5<<<dim3(16, HDIM, BDIM), 512, 0, stream>>>(qkvb, hb);
    k_gemm3<2,true,false,false,true><<<dim3(256,8), 64, 0, stream>>>(
        hb, wpT + (size_t)l*65536, bp + l*CDIM, xb, CDIM);
    k_ln<<<NTOK/4, 256, 0, stream>>>(xb, hb);
    k_gemm3<2,true,true,true,false><<<dim3(256,8), 64, 0, stream>>>(
        hb, w1T + (size_t)l*65536, b1f + l*CDIM, fh, CDIM);
    k_gemm3<2,true,false,false,true><<<dim3(256,8), 64, 0, stream>>>(
        fh, w2T + (size_t)l*65536, b2 + l*CDIM, xb, CDIM);
  }
  k_poolln<<<32, 256, 0, stream>>>(xb, part);
  k_cls1<<<dim3(2,4), 256, 0, stream>>>(part, Wc1s, bc1f, hid);
  k_cls2<<<1, 256, 0, stream>>>(hid, Wc2, bc2, (float*)d_out);
}

// Round 11
// 568.602 us; speedup vs baseline: 1.1243x; 1.0594x over previous
//
#include <hip/hip_runtime.h>
#include <hip/hip_bf16.h>

#define NTOK 8192      // B*T
#define CDIM 256
#define TDIM 2048
#define BDIM 4
#define HDIM 8
#define HSZ  32
#define LNUM 4
#define BUF  (NTOK*CDIM)
#define QSTR 768       // fused qkv row stride
#define LC   0.0901684400056f   // 2^-4 * log2(e), folded into Wq/bq

typedef __attribute__((ext_vector_type(8))) short short8v;
typedef __attribute__((ext_vector_type(4))) short short4v;
typedef __attribute__((ext_vector_type(4))) float float4v;

static __device__ __forceinline__ short f2bs(float f){
  union { float f; unsigned u; } x; x.f = f;
  unsigned r = x.u + 0x7FFFu + ((x.u >> 16) & 1u);
  return (short)(r >> 16);
}
// pack two fp32 -> bf16x2 (RNE); low = a, high = b
static __device__ __forceinline__ unsigned pkbf(float a, float b){
  union { float f; unsigned u; } x, y; x.f = a; y.f = b;
  unsigned ra = x.u + 0x7FFFu + ((x.u >> 16) & 1u);
  unsigned rb = y.u + 0x7FFFu + ((y.u >> 16) & 1u);
  return __builtin_amdgcn_perm(rb, ra, 0x07060302u);
}
#if __has_builtin(__builtin_amdgcn_exp2f)
static __device__ __forceinline__ float fexp2(float x){ return __builtin_amdgcn_exp2f(x); }
#else
static __device__ __forceinline__ float fexp2(float x){ return __expf(x*0.6931471805599453f); }
#endif

#if __has_builtin(__builtin_amdgcn_mfma_f32_16x16x16bf16_1k)
static __device__ __forceinline__ float4v mfma16(short4v a, short4v b, float4v c){
  return __builtin_amdgcn_mfma_f32_16x16x16bf16_1k(a, b, c, 0, 0, 0);
}
#else
static __device__ __forceinline__ float4v mfma16(short4v a, short4v b, float4v c){
  float4v d;
  asm volatile("v_mfma_f32_16x16x16_bf16 %0, %1, %2, %3\n\ts_nop 7\n\ts_nop 7"
               : "=v"(d) : "v"(a), "v"(b), "v"(c));
  return d;
}
#endif
static __device__ __forceinline__ float4v mfma32(short8v a, short8v b, float4v c){
  return __builtin_amdgcn_mfma_f32_16x16x32_bf16(a, b, c, 0, 0, 0);
}

// ---------------- merged weight prep + bias folding (block-range branch) ----------------
// blocks 0-383: transpose weights to bf16 [N][K] folding LN gains + softmax scale
// blocks 384-447: bq/b1f; 448-511: Wc1s; 512: bc1f
__global__ __launch_bounds__(256) void k_prep2(
    const float* __restrict__ Wq, const float* __restrict__ Wk, const float* __restrict__ Wv,
    const float* __restrict__ Wp, const float* __restrict__ W1, const float* __restrict__ W2,
    const float* __restrict__ l1g, const float* __restrict__ l2g,
    const float* __restrict__ l1b, const float* __restrict__ l2b,
    const float* __restrict__ b1, const float* __restrict__ Wc1, const float* __restrict__ lnfg,
    const float* __restrict__ lnfb, const float* __restrict__ bc1,
    short* __restrict__ qkvT, short* __restrict__ wpT, short* __restrict__ w1T, short* __restrict__ w2T,
    float* __restrict__ bq, float* __restrict__ b1f, float* __restrict__ Wc1s, float* __restrict__ bc1f) {
  const int tid = threadIdx.x;
  const int id = blockIdx.x;
  if (id < 384) {
    __shared__ float tile[64][65];
    int l = id / 96, rr = id % 96;
    const float* src; short* dst; int n0, k0; bool qkvmode; int gsel; float nscale = 1.f;
    if (rr < 48) {
      int tn = rr >> 2, tk = rr & 3;
      n0 = tn*64; k0 = tk*64;
      const float* b3 = (n0 < 256) ? Wq : (n0 < 512 ? Wk : Wv);
      src = b3 + l*65536;
      dst = qkvT + (size_t)l*QSTR*256;
      qkvmode = true; gsel = 1;
      if (n0 < 256) nscale = LC;
    } else {
      int r2 = rr - 48;
      int mat = r2 >> 4, t = r2 & 15;
      int tn = t >> 2, tk = t & 3;
      n0 = tn*64; k0 = tk*64;
      const float* b3 = (mat == 0) ? Wp : (mat == 1 ? W1 : W2);
      src = b3 + l*65536;
      dst = (mat == 0 ? wpT : (mat == 1 ? w1T : w2T)) + l*65536;
      qkvmode = false; gsel = (mat == 1) ? 2 : 0;
    }
    const int cn = tid & 63, rk = tid >> 6;
    #pragma unroll
    for (int i = 0; i < 16; ++i) {
      int kk = rk + i*4;
      int n = n0 + cn, k = k0 + kk;
      float v;
      if (qkvmode) { int nn = n & 255; v = src[((nn>>5)*256 + k)*32 + (nn & 31)]; }
      else         { v = src[k*256 + n]; }
      if (gsel == 1)      v *= l1g[l*256 + k];
      else if (gsel == 2) v *= l2g[l*256 + k];
      tile[kk][cn] = v;
    }
    __syncthreads();
    #pragma unroll
    for (int i = 0; i < 16; ++i) {
      int nn = rk + i*4;
      dst[(size_t)(n0 + nn)*256 + k0 + cn] = f2bs(tile[cn][nn] * nscale);
    }
  } else if (id < 448) {
    __shared__ float red[4][64];
    int bid = id - 384;
    int l = bid >> 4, seg = bid & 15;
    int o = seg*64 + (tid & 63), pp = tid >> 6;
    float s = 0.f;
    if (o < 768) {
      const float* W = (o < 256 ? Wq : (o < 512 ? Wk : Wv)) + l*65536;
      int nn = o & 255, h = nn >> 5, d = nn & 31;
      const float* bv = l1b + l*256;
      for (int k = pp*64; k < pp*64+64; ++k) s = fmaf(bv[k], W[(h*256 + k)*32 + d], s);
    } else {
      const float* W = W1 + l*65536;
      int n = o - 768;
      const float* bv = l2b + l*256;
      for (int k = pp*64; k < pp*64+64; ++k) s = fmaf(bv[k], W[k*256 + n], s);
    }
    red[pp][tid & 63] = s;
    __syncthreads();
    if (tid < 64) {
      float tot = red[0][tid]+red[1][tid]+red[2][tid]+red[3][tid];
      int oo = seg*64 + tid;
      if (oo < 768) bq[l*768 + oo] = tot * (oo < 256 ? LC : 1.f);
      else          b1f[l*256 + (oo-768)] = b1[l*256 + (oo-768)] + tot;
    }
  } else if (id < 512) {
    int base = (id-448)*2048;
    #pragma unroll
    for (int i=0;i<8;++i) {
      int idx2 = base + i*256 + tid;
      Wc1s[idx2] = Wc1[idx2] * lnfg[idx2 >> 9];
    }
  } else {
    for (int u = tid; u < 512; u += 256) {
      float s = bc1[u];
      for (int k=0;k<256;++k) s = fmaf(lnfb[k], Wc1[k*512+u], s);
      bc1f[u] = s;
    }
  }
}

// ---------------- embedding + LN1(layer0) fused: wave per row ----------------
__global__ __launch_bounds__(256) void k_embed2(const int* __restrict__ idx,
    const float* __restrict__ tok, const float* __restrict__ pos,
    float* __restrict__ x, short* __restrict__ y) {
  const int lane = threadIdx.x & 63;
  const int bt = blockIdx.x*4 + (threadIdx.x >> 6);
  const int t = bt & (TDIM-1);
  float4 tv = *(const float4*)&tok[(size_t)idx[bt]*CDIM + lane*4];
  float4 pv = *(const float4*)&pos[(size_t)t*CDIM + lane*4];
  float4 v = make_float4(tv.x+pv.x, tv.y+pv.y, tv.z+pv.z, tv.w+pv.w);
  *(float4*)&x[(size_t)bt*CDIM + lane*4] = v;
  float s1 = (v.x+v.y) + (v.z+v.w);
  float s2 = fmaf(v.x,v.x, fmaf(v.y,v.y, fmaf(v.z,v.z, v.w*v.w)));
  #pragma unroll
  for (int off=32; off>0; off>>=1) { s1 += __shfl_xor(s1, off, 64); s2 += __shfl_xor(s2, off, 64); }
  float mean = s1*(1.f/CDIM);
  float inv  = rsqrtf(s2*(1.f/CDIM) - mean*mean + 1e-5f);
  float cc = -mean*inv;
  union { unsigned u[2]; short4v s; } o;
  o.u[0] = pkbf(fmaf(v.x,inv,cc), fmaf(v.y,inv,cc));
  o.u[1] = pkbf(fmaf(v.z,inv,cc), fmaf(v.w,inv,cc));
  *(short4v*)&y[(size_t)bt*CDIM + lane*4] = o.s;
}

// ---------------- LDS-free MFMA GEMM (QKV / W1): C = A(bf16) x Bt[N][256](bf16) ----------------
template<int NF, bool BIAS, bool RELU, bool OUTBF16, bool ACCUM>
__global__ __launch_bounds__(64) void k_gemm3(const short* __restrict__ A,
    const short* __restrict__ Bt, const float* __restrict__ bias, void* __restrict__ Cv,
    int outstride) {
  const int lane = threadIdx.x;
  const int q4 = lane >> 4, r = lane & 15;
  const int blockRow = blockIdx.x * 32;
  const int blockCol = blockIdx.y * (NF*16);
  float4v acc[2][NF];
  #pragma unroll
  for (int i=0;i<2;++i)
    #pragma unroll
    for (int j=0;j<NF;++j) acc[i][j] = (float4v){0,0,0,0};
  #pragma unroll
  for (int k0 = 0; k0 < 256; k0 += 32) {
    short8v a0 = *(const short8v*)&A[(size_t)(blockRow +      r)*CDIM + k0 + q4*8];
    short8v a1 = *(const short8v*)&A[(size_t)(blockRow + 16 + r)*CDIM + k0 + q4*8];
    #pragma unroll
    for (int nf=0; nf<NF; ++nf) {
      short8v bf = *(const short8v*)&Bt[(size_t)(blockCol + nf*16 + r)*256 + k0 + q4*8];
      acc[0][nf] = mfma32(a0, bf, acc[0][nf]);
      acc[1][nf] = mfma32(a1, bf, acc[1][nf]);
    }
  }
  #pragma unroll
  for (int mf=0; mf<2; ++mf)
    #pragma unroll
    for (int nf=0; nf<NF; ++nf) {
      int col = blockCol + nf*16 + r;
      float bb = BIAS ? bias[col] : 0.f;
      #pragma unroll
      for (int reg=0; reg<4; ++reg) {
        int row = blockRow + mf*16 + q4*4 + reg;
        float v = acc[mf][nf][reg] + bb;
        if (RELU) v = fmaxf(v, 0.f);
        size_t oi = (size_t)row*outstride + col;
        if (ACCUM)        ((float*)Cv)[oi] += v;
        else if (OUTBF16) ((short*)Cv)[oi] = f2bs(v);
        else              ((float*)Cv)[oi] = v;
      }
    }
}

// ---------------- fused GEMM + residual + LN: X' = A x Bt + bias + X; Y = stdize(X') ----------
// 512 thr = 8 waves: wm = w&1 (16-row half), wn = w>>1 (64-col quarter); block = 32 x 256.
// Row stats computed from accumulators (shfl within 16-lane groups + LDS combine over wn).
template<bool WRITELN>
__global__ __launch_bounds__(512) void k_gemmres(const short* __restrict__ A,
    const short* __restrict__ Bt, const float* __restrict__ bias,
    float* __restrict__ X, short* __restrict__ Y) {
  __shared__ float S1[32][4], S2[32][4];
  const int tid = threadIdx.x;
  const int w = tid >> 6, lane = tid & 63;
  const int q4 = lane >> 4, r = lane & 15;
  const int wm = w & 1, wn = w >> 1;
  const int row0 = blockIdx.x * 32 + wm*16;
  const int col0 = wn*64;
  float4v acc[4];
  #pragma unroll
  for (int j=0;j<4;++j) acc[j] = (float4v){0,0,0,0};
  #pragma unroll
  for (int k0 = 0; k0 < 256; k0 += 32) {
    short8v a0 = *(const short8v*)&A[(size_t)(row0 + r)*CDIM + k0 + q4*8];
    #pragma unroll
    for (int nf=0; nf<4; ++nf) {
      short8v bf = *(const short8v*)&Bt[(size_t)(col0 + nf*16 + r)*256 + k0 + q4*8];
      acc[nf] = mfma32(a0, bf, acc[nf]);
    }
  }
  // residual add, write X', accumulate row stats
  float v[4][4];   // [nf][reg]
  float sw1[4], sw2[4];
  #pragma unroll
  for (int reg=0; reg<4; ++reg) {
    int row = row0 + q4*4 + reg;
    float s1 = 0.f, s2 = 0.f;
    #pragma unroll
    for (int nf=0; nf<4; ++nf) {
      int col = col0 + nf*16 + r;
      float t = acc[nf][reg] + bias[col] + X[(size_t)row*CDIM + col];
      v[nf][reg] = t;
      X[(size_t)row*CDIM + col] = t;
      s1 += t; s2 = fmaf(t, t, s2);
    }
    if (WRITELN) {
      #pragma unroll
      for (int off=1; off<16; off<<=1) { s1 += __shfl_xor(s1, off, 64); s2 += __shfl_xor(s2, off, 64); }
      sw1[reg] = s1; sw2[reg] = s2;
    }
  }
  if (WRITELN) {
    if (r == 0) {
      #pragma unroll
      for (int reg=0; reg<4; ++reg) {
        S1[wm*16 + q4*4 + reg][wn] = sw1[reg];
        S2[wm*16 + q4*4 + reg][wn] = sw2[reg];
      }
    }
    __syncthreads();
    #pragma unroll
    for (int reg=0; reg<4; ++reg) {
      int ri = wm*16 + q4*4 + reg;
      float s1 = (S1[ri][0]+S1[ri][1]) + (S1[ri][2]+S1[ri][3]);
      float s2 = (S2[ri][0]+S2[ri][1]) + (S2[ri][2]+S2[ri][3]);
      float mean = s1*(1.f/CDIM);
      float inv  = rsqrtf(s2*(1.f/CDIM) - mean*mean + 1e-5f);
      float cc = -mean*inv;
      int row = row0 + q4*4 + reg;
      #pragma unroll
      for (int nf=0; nf<4; ++nf) {
        int col = col0 + nf*16 + r;
        Y[(size_t)row*CDIM + col] = f2bs(fmaf(v[nf][reg], inv, cc));
      }
    }
  }
}

// ---------------- MFMA flash attention: double-buffered staging, 1 barrier/tile ----------------
#define KS_STRIDE 40
#define VT_STRIDE 76
__global__ __launch_bounds__(512) void k_attn5(const short* __restrict__ qkv,
    short* __restrict__ O) {
  __shared__ __align__(16) short Ks[2][64*KS_STRIDE];
  __shared__ __align__(16) short Vt[2][32*VT_STRIDE];
  const int tid = threadIdx.x;
  const int w = tid >> 6, lane = tid & 63;
  const int q4 = lane >> 4, r = lane & 15;
  const int b = blockIdx.z, h = blockIdx.y;
  const int rowbase = blockIdx.x*128 + w*16;
  short8v Qf = *(const short8v*)&qkv[((size_t)(b*TDIM + rowbase + r))*QSTR + h*HSZ + q4*8];
  float4v o0 = {0,0,0,0}, o1 = {0,0,0,0};
  float l0 = 0.f;
  const bool isV = tid >= 256;
  const int t2 = tid & 255;
  const int skey = t2 >> 2, kd0 = (t2 & 3)*8;
  const int kp = t2 & 31, dg = t2 >> 5;
  const short* kvbase = qkv + (size_t)b*TDIM*QSTR + h*HSZ;
  short8v kv; short4v vv0, vv1;
  if (isV) {
    vv0 = *(const short4v*)&kvbase[(size_t)(2*kp)*QSTR   + 2*CDIM + dg*4];
    vv1 = *(const short4v*)&kvbase[(size_t)(2*kp+1)*QSTR + 2*CDIM + dg*4];
  } else {
    kv = *(const short8v*)&kvbase[(size_t)skey*QSTR + CDIM + kd0];
  }
  int p = 0;
  for (int s0 = 0; s0 < TDIM; s0 += 64, p ^= 1) {
    if (isV) {
      union { short4v s; unsigned u[2]; } a, c;
      a.s = vv0; c.s = vv1;
      *(unsigned*)&Vt[p][(dg*4+0)*VT_STRIDE + 2*kp] = __builtin_amdgcn_perm(c.u[0], a.u[0], 0x05040100u);
      *(unsigned*)&Vt[p][(dg*4+1)*VT_STRIDE + 2*kp] = __builtin_amdgcn_perm(c.u[0], a.u[0], 0x07060302u);
      *(unsigned*)&Vt[p][(dg*4+2)*VT_STRIDE + 2*kp] = __builtin_amdgcn_perm(c.u[1], a.u[1], 0x05040100u);
      *(unsigned*)&Vt[p][(dg*4+3)*VT_STRIDE + 2*kp] = __builtin_amdgcn_perm(c.u[1], a.u[1], 0x07060302u);
    } else {
      *(short8v*)&Ks[p][skey*KS_STRIDE + kd0] = kv;
    }
    if (s0 + 64 < TDIM) {
      const short* nb = kvbase + (size_t)(s0+64)*QSTR;
      if (isV) {
        vv0 = *(const short4v*)&nb[(size_t)(2*kp)*QSTR   + 2*CDIM + dg*4];
        vv1 = *(const short4v*)&nb[(size_t)(2*kp+1)*QSTR + 2*CDIM + dg*4];
      } else {
        kv = *(const short8v*)&nb[(size_t)skey*QSTR + CDIM + kd0];
      }
    }
    __syncthreads();
    #pragma unroll
    for (int ks = 0; ks < 4; ++ks) {
      short8v Kf = *(const short8v*)&Ks[p][(ks*16 + r)*KS_STRIDE + q4*8];
      float4v sv = mfma32(Kf, Qf, (float4v){0,0,0,0});
      short4v Vf0 = *(const short4v*)&Vt[p][r*VT_STRIDE + ks*16 + q4*4];
      short4v Vf1 = *(const short4v*)&Vt[p][(16+r)*VT_STRIDE + ks*16 + q4*4];
      float p0 = fexp2(sv[0]), p1 = fexp2(sv[1]);
      float p2 = fexp2(sv[2]), p3 = fexp2(sv[3]);
      l0 += (p0+p1) + (p2+p3);
      union { unsigned u[2]; short4v s; } P;
      P.u[0] = pkbf(p0, p1); P.u[1] = pkbf(p2, p3);
      o0 = mfma16(P.s, Vf0, o0);
      o1 = mfma16(P.s, Vf1, o1);
    }
  }
  l0 += __shfl_xor(l0, 16, 64); l0 += __shfl_xor(l0, 32, 64);
  #pragma unroll
  for (int reg=0; reg<4; ++reg) {
    int qrow = q4*4 + reg;
    float i0 = 1.f / __shfl(l0, qrow, 64);
    short* op = O + ((size_t)(b*TDIM + rowbase + qrow))*CDIM + h*HSZ;
    op[r]    = f2bs(o0[reg]*i0);
    op[16+r] = f2bs(o1[reg]*i0);
  }
}

// ---------------- fused final-LN + mean-pool ----------------
__global__ __launch_bounds__(256) void k_poolln(const float* __restrict__ X, float* __restrict__ part) {
  __shared__ float red[4][256];
  int b = blockIdx.x >> 3, chunk = blockIdx.x & 7;
  int wv = threadIdx.x >> 6, lane = threadIdx.x & 63;
  int base = b*TDIM + chunk*256 + wv*64;
  float a0=0,a1=0,a2=0,a3=0;
  for (int rr=0; rr<64; ++rr) {
    float4 v = *(const float4*)&X[(size_t)(base+rr)*CDIM + lane*4];
    float s1 = (v.x+v.y)+(v.z+v.w);
    float s2 = fmaf(v.x,v.x, fmaf(v.y,v.y, fmaf(v.z,v.z, v.w*v.w)));
    #pragma unroll
    for (int off=32; off>0; off>>=1) { s1 += __shfl_xor(s1,off,64); s2 += __shfl_xor(s2,off,64); }
    float mean = s1*(1.f/256.f);
    float inv  = rsqrtf(s2*(1.f/256.f) - mean*mean + 1e-5f);
    a0 = fmaf(v.x-mean, inv, a0); a1 = fmaf(v.y-mean, inv, a1);
    a2 = fmaf(v.z-mean, inv, a2); a3 = fmaf(v.w-mean, inv, a3);
  }
  red[wv][lane*4+0]=a0; red[wv][lane*4+1]=a1; red[wv][lane*4+2]=a2; red[wv][lane*4+3]=a3;
  __syncthreads();
  int c = threadIdx.x;
  part[blockIdx.x*256 + c] = (red[0][c]+red[1][c]+red[2][c]+red[3][c]) * (1.f/2048.f);
}

// ---------------- fused classifier: combine + fc1 + relu + fc2 + softmax (one block) --------
__global__ __launch_bounds__(512) void k_cls(const float* __restrict__ part,
    const float* __restrict__ Wc1s, const float* __restrict__ bc1f,
    const float* __restrict__ Wc2, const float* __restrict__ bc2, float* __restrict__ out) {
  __shared__ float se[4][256];
  __shared__ float sh[4][512];
  __shared__ float red[160];
  __shared__ float sl[40];
  const int t = threadIdx.x;
  for (int j=t; j<1024; j+=512) {
    int b = j >> 8, c = j & 255;
    float s = 0.f;
    #pragma unroll
    for (int ch=0; ch<8; ++ch) s += part[(b*8+ch)*256 + c];
    se[b][c] = s;
  }
  __syncthreads();
  {
    float bb = bc1f[t];
    float a0=bb, a1=bb, a2=bb, a3=bb;
    for (int c=0; c<256; ++c) {
      float w2 = Wc1s[c*512 + t];
      a0 = fmaf(se[0][c], w2, a0); a1 = fmaf(se[1][c], w2, a1);
      a2 = fmaf(se[2][c], w2, a2); a3 = fmaf(se[3][c], w2, a3);
    }
    sh[0][t]=fmaxf(a0,0.f); sh[1][t]=fmaxf(a1,0.f);
    sh[2][t]=fmaxf(a2,0.f); sh[3][t]=fmaxf(a3,0.f);
  }
  __syncthreads();
  if (t < 160) {
    int o = t >> 2, pp = t & 3;
    int b = o / 10, j = o - b*10;
    const float* hp = &sh[b][pp*128];
    float s = 0.f;
    #pragma unroll 8
    for (int u=0; u<128; ++u) s = fmaf(hp[u], Wc2[(pp*128+u)*10 + j], s);
    red[t] = s;
  }
  __syncthreads();
  if (t < 40) sl[t] = (red[t*4]+red[t*4+1]) + (red[t*4+2]+red[t*4+3]) + bc2[t%10];
  __syncthreads();
  if (t < 4) {
    float mx = -1e30f;
    for (int j=0;j<10;++j) mx = fmaxf(mx, sl[t*10+j]);
    float e[10], sum = 0.f;
    for (int j=0;j<10;++j) { e[j] = __expf(sl[t*10+j]-mx); sum += e[j]; }
    float inv = 1.f/sum;
    for (int j=0;j<10;++j) out[t*10+j] = e[j]*inv;
  }
}

extern "C" void kernel_launch(void* const* d_in, const int* in_sizes, int n_in,
                              void* d_out, int out_size, void* d_ws, size_t ws_size,
                              hipStream_t stream) {
  const int*   idx = (const int*)d_in[0];
  const float* tok = (const float*)d_in[1];
  const float* pos = (const float*)d_in[2];
  const float* Wq  = (const float*)d_in[3];
  const float* Wk  = (const float*)d_in[4];
  const float* Wv  = (const float*)d_in[5];
  const float* Wp  = (const float*)d_in[6];
  const float* bp  = (const float*)d_in[7];
  const float* l1g = (const float*)d_in[8];
  const float* l1b = (const float*)d_in[9];
  const float* l2g = (const float*)d_in[10];
  const float* l2b = (const float*)d_in[11];
  const float* W1  = (const float*)d_in[12];
  const float* b1  = (const float*)d_in[13];
  const float* W2  = (const float*)d_in[14];
  const float* b2  = (const float*)d_in[15];
  const float* lfg = (const float*)d_in[16];
  const float* lfb = (const float*)d_in[17];
  const float* Wc1 = (const float*)d_in[18];
  const float* bc1 = (const float*)d_in[19];
  const float* Wc2 = (const float*)d_in[20];
  const float* bc2 = (const float*)d_in[21];

  char* p = (char*)d_ws;
  float* xb   = (float*)p;              p += (size_t)BUF*4;        // fp32 residual (8 MB)
  short* hb   = (short*)p;              p += (size_t)BUF*2;        // bf16 LN/attn out (4 MB)
  short* qkvb = (short*)p;              p += (size_t)NTOK*QSTR*2;  // bf16 fused QKV (12 MB)
  float* part = (float*)p;              p += 32*256*4;
  short* wqkvT = (short*)p;             p += (size_t)LNUM*QSTR*256*2;
  short* wpT   = (short*)p;             p += (size_t)LNUM*65536*2;
  short* w1T   = (short*)p;             p += (size_t)LNUM*65536*2;
  short* w2T   = (short*)p;             p += (size_t)LNUM*65536*2;
  float* bq    = (float*)p;             p += (size_t)LNUM*768*4;
  float* b1f   = (float*)p;             p += (size_t)LNUM*256*4;
  float* Wc1s  = (float*)p;             p += (size_t)256*512*4;
  float* bc1f  = (float*)p;             p += 512*4;
  short* fh    = qkvb;                  // FFN hidden reuses qkv buffer

  k_prep2<<<513, 256, 0, stream>>>(Wq, Wk, Wv, Wp, W1, W2, l1g, l2g, l1b, l2b,
                                   b1, Wc1, lfg, lfb, bc1,
                                   wqkvT, wpT, w1T, w2T, bq, b1f, Wc1s, bc1f);
  k_embed2<<<NTOK/4, 256, 0, stream>>>(idx, tok, pos, xb, hb);
  for (int l = 0; l < LNUM; ++l) {
    k_gemm3<4,true,false,true,false><<<dim3(256,12), 64, 0, stream>>>(
        hb, wqkvT + (size_t)l*QSTR*256, bq + l*768, qkvb, QSTR);
    k_attn5<<<dim3(16, HDIM, BDIM), 512, 0, stream>>>(qkvb, hb);
    k_gemmres<true><<<256, 512, 0, stream>>>(                     // Wp + residual + LN2
        hb, wpT + (size_t)l*65536, bp + l*CDIM, xb, hb);
    k_gemm3<2,true,true,true,false><<<dim3(256,8), 64, 0, stream>>>(
        hb, w1T + (size_t)l*65536, b1f + l*CDIM, fh, CDIM);
    if (l < LNUM-1) {
      k_gemmres<true><<<256, 512, 0, stream>>>(                   // W2 + residual + LN1(next)
          fh, w2T + (size_t)l*65536, b2 + l*CDIM, xb, hb);
    } else {
      k_gemmres<false><<<256, 512, 0, stream>>>(
          fh, w2T + (size_t)l*65536, b2 + l*CDIM, xb, hb);
    }
  }
  k_poolln<<<32, 256, 0, stream>>>(xb, part);
  k_cls<<<1, 512, 0, stream>>>(part, Wc1s, bc1f, Wc2, bc2, (float*)d_out);
}

// Round 12
// 556.897 us; speedup vs baseline: 1.1479x; 1.0210x over previous
//
#include <hip/hip_runtime.h>
#include <hip/hip_bf16.h>

#define NTOK 8192      // B*T
#define CDIM 256
#define TDIM 2048
#define BDIM 4
#define HDIM 8
#define HSZ  32
#define LNUM 4
#define BUF  (NTOK*CDIM)
#define QSTR 768       // fused qkv row stride
#define LC   0.0901684400056f   // 2^-4 * log2(e), folded into Wq/bq

typedef __attribute__((ext_vector_type(8))) short short8v;
typedef __attribute__((ext_vector_type(4))) short short4v;
typedef __attribute__((ext_vector_type(4))) float float4v;

static __device__ __forceinline__ short f2bs(float f){
  union { float f; unsigned u; } x; x.f = f;
  unsigned r = x.u + 0x7FFFu + ((x.u >> 16) & 1u);
  return (short)(r >> 16);
}
// pack two fp32 -> bf16x2 (RNE); low = a, high = b
static __device__ __forceinline__ unsigned pkbf(float a, float b){
  union { float f; unsigned u; } x, y; x.f = a; y.f = b;
  unsigned ra = x.u + 0x7FFFu + ((x.u >> 16) & 1u);
  unsigned rb = y.u + 0x7FFFu + ((y.u >> 16) & 1u);
  return __builtin_amdgcn_perm(rb, ra, 0x07060302u);
}
#if __has_builtin(__builtin_amdgcn_exp2f)
static __device__ __forceinline__ float fexp2(float x){ return __builtin_amdgcn_exp2f(x); }
#else
static __device__ __forceinline__ float fexp2(float x){ return __expf(x*0.6931471805599453f); }
#endif

#if __has_builtin(__builtin_amdgcn_mfma_f32_16x16x16bf16_1k)
static __device__ __forceinline__ float4v mfma16(short4v a, short4v b, float4v c){
  return __builtin_amdgcn_mfma_f32_16x16x16bf16_1k(a, b, c, 0, 0, 0);
}
#else
static __device__ __forceinline__ float4v mfma16(short4v a, short4v b, float4v c){
  float4v d;
  asm volatile("v_mfma_f32_16x16x16_bf16 %0, %1, %2, %3\n\ts_nop 7\n\ts_nop 7"
               : "=v"(d) : "v"(a), "v"(b), "v"(c));
  return d;
}
#endif
static __device__ __forceinline__ float4v mfma32(short8v a, short8v b, float4v c){
  return __builtin_amdgcn_mfma_f32_16x16x32_bf16(a, b, c, 0, 0, 0);
}

// ---------------- merged weight prep + bias folding ----------------
__global__ __launch_bounds__(256) void k_prep2(
    const float* __restrict__ Wq, const float* __restrict__ Wk, const float* __restrict__ Wv,
    const float* __restrict__ Wp, const float* __restrict__ W1, const float* __restrict__ W2,
    const float* __restrict__ l1g, const float* __restrict__ l2g,
    const float* __restrict__ l1b, const float* __restrict__ l2b,
    const float* __restrict__ b1, const float* __restrict__ Wc1, const float* __restrict__ lnfg,
    const float* __restrict__ lnfb, const float* __restrict__ bc1,
    short* __restrict__ qkvT, short* __restrict__ wpT, short* __restrict__ w1T, short* __restrict__ w2T,
    float* __restrict__ bq, float* __restrict__ b1f, float* __restrict__ Wc1s, float* __restrict__ bc1f) {
  const int tid = threadIdx.x;
  const int id = blockIdx.x;
  if (id < 384) {
    __shared__ float tile[64][65];
    int l = id / 96, rr = id % 96;
    const float* src; short* dst; int n0, k0; bool qkvmode; int gsel; float nscale = 1.f;
    if (rr < 48) {
      int tn = rr >> 2, tk = rr & 3;
      n0 = tn*64; k0 = tk*64;
      const float* b3 = (n0 < 256) ? Wq : (n0 < 512 ? Wk : Wv);
      src = b3 + l*65536;
      dst = qkvT + (size_t)l*QSTR*256;
      qkvmode = true; gsel = 1;
      if (n0 < 256) nscale = LC;
    } else {
      int r2 = rr - 48;
      int mat = r2 >> 4, t = r2 & 15;
      int tn = t >> 2, tk = t & 3;
      n0 = tn*64; k0 = tk*64;
      const float* b3 = (mat == 0) ? Wp : (mat == 1 ? W1 : W2);
      src = b3 + l*65536;
      dst = (mat == 0 ? wpT : (mat == 1 ? w1T : w2T)) + l*65536;
      qkvmode = false; gsel = (mat == 1) ? 2 : 0;
    }
    const int cn = tid & 63, rk = tid >> 6;
    #pragma unroll
    for (int i = 0; i < 16; ++i) {
      int kk = rk + i*4;
      int n = n0 + cn, k = k0 + kk;
      float v;
      if (qkvmode) { int nn = n & 255; v = src[((nn>>5)*256 + k)*32 + (nn & 31)]; }
      else         { v = src[k*256 + n]; }
      if (gsel == 1)      v *= l1g[l*256 + k];
      else if (gsel == 2) v *= l2g[l*256 + k];
      tile[kk][cn] = v;
    }
    __syncthreads();
    #pragma unroll
    for (int i = 0; i < 16; ++i) {
      int nn = rk + i*4;
      dst[(size_t)(n0 + nn)*256 + k0 + cn] = f2bs(tile[cn][nn] * nscale);
    }
  } else if (id < 448) {
    __shared__ float red[4][64];
    int bid = id - 384;
    int l = bid >> 4, seg = bid & 15;
    int o = seg*64 + (tid & 63), pp = tid >> 6;
    float s = 0.f;
    if (o < 768) {
      const float* W = (o < 256 ? Wq : (o < 512 ? Wk : Wv)) + l*65536;
      int nn = o & 255, h = nn >> 5, d = nn & 31;
      const float* bv = l1b + l*256;
      for (int k = pp*64; k < pp*64+64; ++k) s = fmaf(bv[k], W[(h*256 + k)*32 + d], s);
    } else {
      const float* W = W1 + l*65536;
      int n = o - 768;
      const float* bv = l2b + l*256;
      for (int k = pp*64; k < pp*64+64; ++k) s = fmaf(bv[k], W[k*256 + n], s);
    }
    red[pp][tid & 63] = s;
    __syncthreads();
    if (tid < 64) {
      float tot = red[0][tid]+red[1][tid]+red[2][tid]+red[3][tid];
      int oo = seg*64 + tid;
      if (oo < 768) bq[l*768 + oo] = tot * (oo < 256 ? LC : 1.f);
      else          b1f[l*256 + (oo-768)] = b1[l*256 + (oo-768)] + tot;
    }
  } else if (id < 512) {
    int base = (id-448)*2048;
    #pragma unroll
    for (int i=0;i<8;++i) {
      int idx2 = base + i*256 + tid;
      Wc1s[idx2] = Wc1[idx2] * lnfg[idx2 >> 9];
    }
  } else {
    for (int u = tid; u < 512; u += 256) {
      float s = bc1[u];
      for (int k=0;k<256;++k) s = fmaf(lnfb[k], Wc1[k*512+u], s);
      bc1f[u] = s;
    }
  }
}

// ---------------- embedding + LN1(layer0) fused: wave per row ----------------
__global__ __launch_bounds__(256) void k_embed2(const int* __restrict__ idx,
    const float* __restrict__ tok, const float* __restrict__ pos,
    float* __restrict__ x, short* __restrict__ y) {
  const int lane = threadIdx.x & 63;
  const int bt = blockIdx.x*4 + (threadIdx.x >> 6);
  const int t = bt & (TDIM-1);
  float4 tv = *(const float4*)&tok[(size_t)idx[bt]*CDIM + lane*4];
  float4 pv = *(const float4*)&pos[(size_t)t*CDIM + lane*4];
  float4 v = make_float4(tv.x+pv.x, tv.y+pv.y, tv.z+pv.z, tv.w+pv.w);
  *(float4*)&x[(size_t)bt*CDIM + lane*4] = v;
  float s1 = (v.x+v.y) + (v.z+v.w);
  float s2 = fmaf(v.x,v.x, fmaf(v.y,v.y, fmaf(v.z,v.z, v.w*v.w)));
  #pragma unroll
  for (int off=32; off>0; off>>=1) { s1 += __shfl_xor(s1, off, 64); s2 += __shfl_xor(s2, off, 64); }
  float mean = s1*(1.f/CDIM);
  float inv  = rsqrtf(s2*(1.f/CDIM) - mean*mean + 1e-5f);
  float cc = -mean*inv;
  union { unsigned u[2]; short4v s; } o;
  o.u[0] = pkbf(fmaf(v.x,inv,cc), fmaf(v.y,inv,cc));
  o.u[1] = pkbf(fmaf(v.z,inv,cc), fmaf(v.w,inv,cc));
  *(short4v*)&y[(size_t)bt*CDIM + lane*4] = o.s;
}

// ---------------- LDS-free MFMA GEMM (QKV): C = A(bf16) x Bt[N][256](bf16) ----------------
template<int NF, bool BIAS, bool RELU, bool OUTBF16, bool ACCUM>
__global__ __launch_bounds__(64) void k_gemm3(const short* __restrict__ A,
    const short* __restrict__ Bt, const float* __restrict__ bias, void* __restrict__ Cv,
    int outstride) {
  const int lane = threadIdx.x;
  const int q4 = lane >> 4, r = lane & 15;
  const int blockRow = blockIdx.x * 32;
  const int blockCol = blockIdx.y * (NF*16);
  float4v acc[2][NF];
  #pragma unroll
  for (int i=0;i<2;++i)
    #pragma unroll
    for (int j=0;j<NF;++j) acc[i][j] = (float4v){0,0,0,0};
  #pragma unroll
  for (int k0 = 0; k0 < 256; k0 += 32) {
    short8v a0 = *(const short8v*)&A[(size_t)(blockRow +      r)*CDIM + k0 + q4*8];
    short8v a1 = *(const short8v*)&A[(size_t)(blockRow + 16 + r)*CDIM + k0 + q4*8];
    #pragma unroll
    for (int nf=0; nf<NF; ++nf) {
      short8v bf = *(const short8v*)&Bt[(size_t)(blockCol + nf*16 + r)*256 + k0 + q4*8];
      acc[0][nf] = mfma32(a0, bf, acc[0][nf]);
      acc[1][nf] = mfma32(a1, bf, acc[1][nf]);
    }
  }
  #pragma unroll
  for (int mf=0; mf<2; ++mf)
    #pragma unroll
    for (int nf=0; nf<NF; ++nf) {
      int col = blockCol + nf*16 + r;
      float bb = BIAS ? bias[col] : 0.f;
      #pragma unroll
      for (int reg=0; reg<4; ++reg) {
        int row = blockRow + mf*16 + q4*4 + reg;
        float v = acc[mf][nf][reg] + bb;
        if (RELU) v = fmaxf(v, 0.f);
        size_t oi = (size_t)row*outstride + col;
        if (ACCUM)        ((float*)Cv)[oi] += v;
        else if (OUTBF16) ((short*)Cv)[oi] = f2bs(v);
        else              ((float*)Cv)[oi] = v;
      }
    }
}

// ---------------- fused GEMM + residual + LN (Wp path) ----------------
template<bool WRITELN>
__global__ __launch_bounds__(512) void k_gemmres(const short* __restrict__ A,
    const short* __restrict__ Bt, const float* __restrict__ bias,
    float* __restrict__ X, short* __restrict__ Y) {
  __shared__ float S1[32][4], S2[32][4];
  const int tid = threadIdx.x;
  const int w = tid >> 6, lane = tid & 63;
  const int q4 = lane >> 4, r = lane & 15;
  const int wm = w & 1, wn = w >> 1;
  const int row0 = blockIdx.x * 32 + wm*16;
  const int col0 = wn*64;
  float4v acc[4];
  #pragma unroll
  for (int j=0;j<4;++j) acc[j] = (float4v){0,0,0,0};
  #pragma unroll
  for (int k0 = 0; k0 < 256; k0 += 32) {
    short8v a0 = *(const short8v*)&A[(size_t)(row0 + r)*CDIM + k0 + q4*8];
    #pragma unroll
    for (int nf=0; nf<4; ++nf) {
      short8v bf = *(const short8v*)&Bt[(size_t)(col0 + nf*16 + r)*256 + k0 + q4*8];
      acc[nf] = mfma32(a0, bf, acc[nf]);
    }
  }
  float v[4][4];
  float sw1[4], sw2[4];
  #pragma unroll
  for (int reg=0; reg<4; ++reg) {
    int row = row0 + q4*4 + reg;
    float s1 = 0.f, s2 = 0.f;
    #pragma unroll
    for (int nf=0; nf<4; ++nf) {
      int col = col0 + nf*16 + r;
      float t = acc[nf][reg] + bias[col] + X[(size_t)row*CDIM + col];
      v[nf][reg] = t;
      X[(size_t)row*CDIM + col] = t;
      s1 += t; s2 = fmaf(t, t, s2);
    }
    if (WRITELN) {
      #pragma unroll
      for (int off=1; off<16; off<<=1) { s1 += __shfl_xor(s1, off, 64); s2 += __shfl_xor(s2, off, 64); }
      sw1[reg] = s1; sw2[reg] = s2;
    }
  }
  if (WRITELN) {
    if (r == 0) {
      #pragma unroll
      for (int reg=0; reg<4; ++reg) {
        S1[wm*16 + q4*4 + reg][wn] = sw1[reg];
        S2[wm*16 + q4*4 + reg][wn] = sw2[reg];
      }
    }
    __syncthreads();
    #pragma unroll
    for (int reg=0; reg<4; ++reg) {
      int ri = wm*16 + q4*4 + reg;
      float s1 = (S1[ri][0]+S1[ri][1]) + (S1[ri][2]+S1[ri][3]);
      float s2 = (S2[ri][0]+S2[ri][1]) + (S2[ri][2]+S2[ri][3]);
      float mean = s1*(1.f/CDIM);
      float inv  = rsqrtf(s2*(1.f/CDIM) - mean*mean + 1e-5f);
      float cc = -mean*inv;
      int row = row0 + q4*4 + reg;
      #pragma unroll
      for (int nf=0; nf<4; ++nf) {
        int col = col0 + nf*16 + r;
        Y[(size_t)row*CDIM + col] = f2bs(fmaf(v[nf][reg], inv, cc));
      }
    }
  }
}

// ---------------- fused FFN: X' += relu(A x W1t + b1f) x W2t + b2; Y = stdize(X') ----------
// 512 thr = 8 waves (wm 16-row half, wn 64-col quarter); hidden tile 32x256 through LDS.
template<bool WRITELN>
__global__ __launch_bounds__(512) void k_ffn(const short* __restrict__ A,
    const short* __restrict__ W1t, const float* __restrict__ b1f,
    const short* __restrict__ W2t, const float* __restrict__ b2,
    float* __restrict__ X, short* __restrict__ Y) {
  __shared__ __align__(16) short Gs[32*264];   // hidden tile, stride 264 (528B = 33*16B)
  __shared__ float S1[32][4], S2[32][4];
  const int tid = threadIdx.x;
  const int w = tid >> 6, lane = tid & 63;
  const int q4 = lane >> 4, r = lane & 15;
  const int wm = w & 1, wn = w >> 1;
  const int row0 = blockIdx.x * 32 + wm*16;
  const int col0 = wn*64;
  float4v acc[4];
  #pragma unroll
  for (int j=0;j<4;++j) acc[j] = (float4v){0,0,0,0};
  #pragma unroll
  for (int k0 = 0; k0 < 256; k0 += 32) {
    short8v a0 = *(const short8v*)&A[(size_t)(row0 + r)*CDIM + k0 + q4*8];
    #pragma unroll
    for (int nf=0; nf<4; ++nf) {
      short8v bf = *(const short8v*)&W1t[(size_t)(col0 + nf*16 + r)*256 + k0 + q4*8];
      acc[nf] = mfma32(a0, bf, acc[nf]);
    }
  }
  #pragma unroll
  for (int nf=0; nf<4; ++nf) {
    int col = col0 + nf*16 + r;
    float bb = b1f[col];
    #pragma unroll
    for (int reg=0; reg<4; ++reg) {
      int rl = wm*16 + q4*4 + reg;
      Gs[rl*264 + col] = f2bs(fmaxf(acc[nf][reg] + bb, 0.f));
    }
  }
  __syncthreads();
  #pragma unroll
  for (int j=0;j<4;++j) acc[j] = (float4v){0,0,0,0};
  #pragma unroll
  for (int k0 = 0; k0 < 256; k0 += 32) {
    short8v a0 = *(const short8v*)&Gs[(wm*16 + r)*264 + k0 + q4*8];
    #pragma unroll
    for (int nf=0; nf<4; ++nf) {
      short8v bf = *(const short8v*)&W2t[(size_t)(col0 + nf*16 + r)*256 + k0 + q4*8];
      acc[nf] = mfma32(a0, bf, acc[nf]);
    }
  }
  float v[4][4];
  float sw1[4], sw2[4];
  #pragma unroll
  for (int reg=0; reg<4; ++reg) {
    int row = row0 + q4*4 + reg;
    float s1 = 0.f, s2 = 0.f;
    #pragma unroll
    for (int nf=0; nf<4; ++nf) {
      int col = col0 + nf*16 + r;
      float t = acc[nf][reg] + b2[col] + X[(size_t)row*CDIM + col];
      v[nf][reg] = t;
      X[(size_t)row*CDIM + col] = t;
      s1 += t; s2 = fmaf(t, t, s2);
    }
    if (WRITELN) {
      #pragma unroll
      for (int off=1; off<16; off<<=1) { s1 += __shfl_xor(s1, off, 64); s2 += __shfl_xor(s2, off, 64); }
      sw1[reg] = s1; sw2[reg] = s2;
    }
  }
  if (WRITELN) {
    if (r == 0) {
      #pragma unroll
      for (int reg=0; reg<4; ++reg) {
        S1[wm*16 + q4*4 + reg][wn] = sw1[reg];
        S2[wm*16 + q4*4 + reg][wn] = sw2[reg];
      }
    }
    __syncthreads();
    #pragma unroll
    for (int reg=0; reg<4; ++reg) {
      int ri = wm*16 + q4*4 + reg;
      float s1 = (S1[ri][0]+S1[ri][1]) + (S1[ri][2]+S1[ri][3]);
      float s2 = (S2[ri][0]+S2[ri][1]) + (S2[ri][2]+S2[ri][3]);
      float mean = s1*(1.f/CDIM);
      float inv  = rsqrtf(s2*(1.f/CDIM) - mean*mean + 1e-5f);
      float cc = -mean*inv;
      int row = row0 + q4*4 + reg;
      #pragma unroll
      for (int nf=0; nf<4; ++nf) {
        int col = col0 + nf*16 + r;
        Y[(size_t)row*CDIM + col] = f2bs(fmaf(v[nf][reg], inv, cc));
      }
    }
  }
}

// ---------------- MFMA flash attention: 128-key tiles, dbuf, conflict-free Vt ----------------
#define KSS 40
#define VTS 140    // 280B rows: Vf b64 reads & V writes <=2-way (free)
__global__ __launch_bounds__(512) void k_attn6(const short* __restrict__ qkv,
    short* __restrict__ O) {
  __shared__ __align__(16) short Ks[2][128*KSS];
  __shared__ __align__(16) short Vt[2][32*VTS];
  const int tid = threadIdx.x;
  const int w = tid >> 6, lane = tid & 63;
  const int q4 = lane >> 4, r = lane & 15;
  const int b = blockIdx.z, h = blockIdx.y;
  const int rowbase = blockIdx.x*128 + w*16;
  short8v Qf = *(const short8v*)&qkv[((size_t)(b*TDIM + rowbase + r))*QSTR + h*HSZ + q4*8];
  float4v o0 = {0,0,0,0}, o1 = {0,0,0,0};
  float l0 = 0.f;
  const bool isV = tid >= 256;
  const int t2 = tid & 255;
  const int kkey = t2 >> 1, kd0 = (t2 & 1)*16;  // K staging: 128 keys x 2 dim-halves
  const int kp = t2 & 63, dg = t2 >> 6;         // V staging: 64 key-pairs x 4 dim-groups of 8
  const short* kvbase = qkv + (size_t)b*TDIM*QSTR + h*HSZ;
  short8v ka, kb2, va, vb;
  if (isV) {
    va = *(const short8v*)&kvbase[(size_t)(2*kp)*QSTR   + 2*CDIM + dg*8];
    vb = *(const short8v*)&kvbase[(size_t)(2*kp+1)*QSTR + 2*CDIM + dg*8];
  } else {
    ka  = *(const short8v*)&kvbase[(size_t)kkey*QSTR + CDIM + kd0];
    kb2 = *(const short8v*)&kvbase[(size_t)kkey*QSTR + CDIM + kd0 + 8];
  }
  int p = 0;
  for (int s0 = 0; s0 < TDIM; s0 += 128, p ^= 1) {
    if (isV) {
      union { short8v s; unsigned u[4]; } A, C;
      A.s = va; C.s = vb;
      #pragma unroll
      for (int j=0;j<4;++j) {
        *(unsigned*)&Vt[p][(dg*8+2*j  )*VTS + 2*kp] = __builtin_amdgcn_perm(C.u[j], A.u[j], 0x05040100u);
        *(unsigned*)&Vt[p][(dg*8+2*j+1)*VTS + 2*kp] = __builtin_amdgcn_perm(C.u[j], A.u[j], 0x07060302u);
      }
    } else {
      *(short8v*)&Ks[p][kkey*KSS + kd0]     = ka;
      *(short8v*)&Ks[p][kkey*KSS + kd0 + 8] = kb2;
    }
    if (s0 + 128 < TDIM) {
      const short* nb = kvbase + (size_t)(s0+128)*QSTR;
      if (isV) {
        va = *(const short8v*)&nb[(size_t)(2*kp)*QSTR   + 2*CDIM + dg*8];
        vb = *(const short8v*)&nb[(size_t)(2*kp+1)*QSTR + 2*CDIM + dg*8];
      } else {
        ka  = *(const short8v*)&nb[(size_t)kkey*QSTR + CDIM + kd0];
        kb2 = *(const short8v*)&nb[(size_t)kkey*QSTR + CDIM + kd0 + 8];
      }
    }
    __syncthreads();
    #pragma unroll
    for (int ks = 0; ks < 8; ++ks) {
      short8v Kf = *(const short8v*)&Ks[p][(ks*16 + r)*KSS + q4*8];
      float4v sv = mfma32(Kf, Qf, (float4v){0,0,0,0});
      short4v Vf0 = *(const short4v*)&Vt[p][r*VTS + ks*16 + q4*4];
      short4v Vf1 = *(const short4v*)&Vt[p][(16+r)*VTS + ks*16 + q4*4];
      float p0 = fexp2(sv[0]), p1 = fexp2(sv[1]);
      float p2 = fexp2(sv[2]), p3 = fexp2(sv[3]);
      l0 += (p0+p1) + (p2+p3);
      union { unsigned u[2]; short4v s; } P;
      P.u[0] = pkbf(p0, p1); P.u[1] = pkbf(p2, p3);
      o0 = mfma16(P.s, Vf0, o0);
      o1 = mfma16(P.s, Vf1, o1);
    }
  }
  l0 += __shfl_xor(l0, 16, 64); l0 += __shfl_xor(l0, 32, 64);
  #pragma unroll
  for (int reg=0; reg<4; ++reg) {
    int qrow = q4*4 + reg;
    float i0 = 1.f / __shfl(l0, qrow, 64);
    short* op = O + ((size_t)(b*TDIM + rowbase + qrow))*CDIM + h*HSZ;
    op[r]    = f2bs(o0[reg]*i0);
    op[16+r] = f2bs(o1[reg]*i0);
  }
}

// ---------------- fused final-LN + mean-pool ----------------
__global__ __launch_bounds__(256) void k_poolln(const float* __restrict__ X, float* __restrict__ part) {
  __shared__ float red[4][256];
  int b = blockIdx.x >> 3, chunk = blockIdx.x & 7;
  int wv = threadIdx.x >> 6, lane = threadIdx.x & 63;
  int base = b*TDIM + chunk*256 + wv*64;
  float a0=0,a1=0,a2=0,a3=0;
  for (int rr=0; rr<64; ++rr) {
    float4 v = *(const float4*)&X[(size_t)(base+rr)*CDIM + lane*4];
    float s1 = (v.x+v.y)+(v.z+v.w);
    float s2 = fmaf(v.x,v.x, fmaf(v.y,v.y, fmaf(v.z,v.z, v.w*v.w)));
    #pragma unroll
    for (int off=32; off>0; off>>=1) { s1 += __shfl_xor(s1,off,64); s2 += __shfl_xor(s2,off,64); }
    float mean = s1*(1.f/256.f);
    float inv  = rsqrtf(s2*(1.f/256.f) - mean*mean + 1e-5f);
    a0 = fmaf(v.x-mean, inv, a0); a1 = fmaf(v.y-mean, inv, a1);
    a2 = fmaf(v.z-mean, inv, a2); a3 = fmaf(v.w-mean, inv, a3);
  }
  red[wv][lane*4+0]=a0; red[wv][lane*4+1]=a1; red[wv][lane*4+2]=a2; red[wv][lane*4+3]=a3;
  __syncthreads();
  int c = threadIdx.x;
  part[blockIdx.x*256 + c] = (red[0][c]+red[1][c]+red[2][c]+red[3][c]) * (1.f/2048.f);
}

// ---------------- fused classifier ----------------
__global__ __launch_bounds__(512) void k_cls(const float* __restrict__ part,
    const float* __restrict__ Wc1s, const float* __restrict__ bc1f,
    const float* __restrict__ Wc2, const float* __restrict__ bc2, float* __restrict__ out) {
  __shared__ float se[4][256];
  __shared__ float sh[4][512];
  __shared__ float red[160];
  __shared__ float sl[40];
  const int t = threadIdx.x;
  for (int j=t; j<1024; j+=512) {
    int b = j >> 8, c = j & 255;
    float s = 0.f;
    #pragma unroll
    for (int ch=0; ch<8; ++ch) s += part[(b*8+ch)*256 + c];
    se[b][c] = s;
  }
  __syncthreads();
  {
    float bb = bc1f[t];
    float a0=bb, a1=bb, a2=bb, a3=bb;
    for (int c=0; c<256; ++c) {
      float w2 = Wc1s[c*512 + t];
      a0 = fmaf(se[0][c], w2, a0); a1 = fmaf(se[1][c], w2, a1);
      a2 = fmaf(se[2][c], w2, a2); a3 = fmaf(se[3][c], w2, a3);
    }
    sh[0][t]=fmaxf(a0,0.f); sh[1][t]=fmaxf(a1,0.f);
    sh[2][t]=fmaxf(a2,0.f); sh[3][t]=fmaxf(a3,0.f);
  }
  __syncthreads();
  if (t < 160) {
    int o = t >> 2, pp = t & 3;
    int b = o / 10, j = o - b*10;
    const float* hp = &sh[b][pp*128];
    float s = 0.f;
    #pragma unroll 8
    for (int u=0; u<128; ++u) s = fmaf(hp[u], Wc2[(pp*128+u)*10 + j], s);
    red[t] = s;
  }
  __syncthreads();
  if (t < 40) sl[t] = (red[t*4]+red[t*4+1]) + (red[t*4+2]+red[t*4+3]) + bc2[t%10];
  __syncthreads();
  if (t < 4) {
    float mx = -1e30f;
    for (int j=0;j<10;++j) mx = fmaxf(mx, sl[t*10+j]);
    float e[10], sum = 0.f;
    for (int j=0;j<10;++j) { e[j] = __expf(sl[t*10+j]-mx); sum += e[j]; }
    float inv = 1.f/sum;
    for (int j=0;j<10;++j) out[t*10+j] = e[j]*inv;
  }
}

extern "C" void kernel_launch(void* const* d_in, const int* in_sizes, int n_in,
                              void* d_out, int out_size, void* d_ws, size_t ws_size,
                              hipStream_t stream) {
  const int*   idx = (const int*)d_in[0];
  const float* tok = (const float*)d_in[1];
  const float* pos = (const float*)d_in[2];
  const float* Wq  = (const float*)d_in[3];
  const float* Wk  = (const float*)d_in[4];
  const float* Wv  = (const float*)d_in[5];
  const float* Wp  = (const float*)d_in[6];
  const float* bp  = (const float*)d_in[7];
  const float* l1g = (const float*)d_in[8];
  const float* l1b = (const float*)d_in[9];
  const float* l2g = (const float*)d_in[10];
  const float* l2b = (const float*)d_in[11];
  const float* W1  = (const float*)d_in[12];
  const float* b1  = (const float*)d_in[13];
  const float* W2  = (const float*)d_in[14];
  const float* b2  = (const float*)d_in[15];
  const float* lfg = (const float*)d_in[16];
  const float* lfb = (const float*)d_in[17];
  const float* Wc1 = (const float*)d_in[18];
  const float* bc1 = (const float*)d_in[19];
  const float* Wc2 = (const float*)d_in[20];
  const float* bc2 = (const float*)d_in[21];

  char* p = (char*)d_ws;
  float* xb   = (float*)p;              p += (size_t)BUF*4;        // fp32 residual (8 MB)
  short* hb   = (short*)p;              p += (size_t)BUF*2;        // bf16 LN/attn out (4 MB)
  short* qkvb = (short*)p;              p += (size_t)NTOK*QSTR*2;  // bf16 fused QKV (12 MB)
  float* part = (float*)p;              p += 32*256*4;
  short* wqkvT = (short*)p;             p += (size_t)LNUM*QSTR*256*2;
  short* wpT   = (short*)p;             p += (size_t)LNUM*65536*2;
  short* w1T   = (short*)p;             p += (size_t)LNUM*65536*2;
  short* w2T   = (short*)p;             p += (size_t)LNUM*65536*2;
  float* bq    = (float*)p;             p += (size_t)LNUM*768*4;
  float* b1f   = (float*)p;             p += (size_t)LNUM*256*4;
  float* Wc1s  = (float*)p;             p += (size_t)256*512*4;
  float* bc1f  = (float*)p;             p += 512*4;

  k_prep2<<<513, 256, 0, stream>>>(Wq, Wk, Wv, Wp, W1, W2, l1g, l2g, l1b, l2b,
                                   b1, Wc1, lfg, lfb, bc1,
                                   wqkvT, wpT, w1T, w2T, bq, b1f, Wc1s, bc1f);
  k_embed2<<<NTOK/4, 256, 0, stream>>>(idx, tok, pos, xb, hb);
  for (int l = 0; l < LNUM; ++l) {
    k_gemm3<4,true,false,true,false><<<dim3(256,12), 64, 0, stream>>>(
        hb, wqkvT + (size_t)l*QSTR*256, bq + l*768, qkvb, QSTR);
    k_attn6<<<dim3(16, HDIM, BDIM), 512, 0, stream>>>(qkvb, hb);
    k_gemmres<true><<<256, 512, 0, stream>>>(                     // Wp + residual + LN2
        hb, wpT + (size_t)l*65536, bp + l*CDIM, xb, hb);
    if (l < LNUM-1) {
      k_ffn<true><<<256, 512, 0, stream>>>(                      // FFN + residual + LN1(next)
          hb, w1T + (size_t)l*65536, b1f + l*CDIM, w2T + (size_t)l*65536, b2 + l*CDIM, xb, hb);
    } else {
      k_ffn<false><<<256, 512, 0, stream>>>(
          hb, w1T + (size_t)l*65536, b1f + l*CDIM, w2T + (size_t)l*65536, b2 + l*CDIM, xb, hb);
    }
  }
  k_poolln<<<32, 256, 0, stream>>>(xb, part);
  k_cls<<<1, 512, 0, stream>>>(part, Wc1s, bc1f, Wc2, bc2, (float*)d_out);
}

// Round 13
// 552.254 us; speedup vs baseline: 1.1576x; 1.0084x over previous
//
#include <hip/hip_runtime.h>
#include <hip/hip_bf16.h>

#define NTOK 8192      // B*T
#define CDIM 256
#define TDIM 2048
#define BDIM 4
#define HDIM 8
#define HSZ  32
#define LNUM 4
#define BUF  (NTOK*CDIM)
#define QSTR 768       // fused qkv row stride
#define LC   0.0901684400056f   // 2^-4 * log2(e), folded into Wq/bq

typedef __attribute__((ext_vector_type(8))) short short8v;
typedef __attribute__((ext_vector_type(4))) short short4v;
typedef __attribute__((ext_vector_type(4))) float float4v;

// ---- fp32 -> bf16 pack helpers: HW v_cvt_pk_bf16_f32 when available (1 op), SW RNE fallback ----
#if __has_builtin(__builtin_amdgcn_cvt_pk_bf16_f32)
static __device__ __forceinline__ unsigned pkbf(float a, float b){
  auto t = __builtin_amdgcn_cvt_pk_bf16_f32(a, b);
  union { decltype(t) v; unsigned u; } cv; cv.v = t;
  return cv.u;
}
static __device__ __forceinline__ short f2bs(float f){
  auto t = __builtin_amdgcn_cvt_pk_bf16_f32(f, f);
  union { decltype(t) v; unsigned u; } cv; cv.v = t;
  return (short)(cv.u & 0xFFFFu);
}
#else
static __device__ __forceinline__ short f2bs(float f){
  union { float f; unsigned u; } x; x.f = f;
  unsigned r = x.u + 0x7FFFu + ((x.u >> 16) & 1u);
  return (short)(r >> 16);
}
static __device__ __forceinline__ unsigned pkbf(float a, float b){
  union { float f; unsigned u; } x, y; x.f = a; y.f = b;
  unsigned ra = x.u + 0x7FFFu + ((x.u >> 16) & 1u);
  unsigned rb = y.u + 0x7FFFu + ((y.u >> 16) & 1u);
  return __builtin_amdgcn_perm(rb, ra, 0x07060302u);
}
#endif
#if __has_builtin(__builtin_amdgcn_exp2f)
static __device__ __forceinline__ float fexp2(float x){ return __builtin_amdgcn_exp2f(x); }
#else
static __device__ __forceinline__ float fexp2(float x){ return __expf(x*0.6931471805599453f); }
#endif

#if __has_builtin(__builtin_amdgcn_mfma_f32_16x16x16bf16_1k)
static __device__ __forceinline__ float4v mfma16(short4v a, short4v b, float4v c){
  return __builtin_amdgcn_mfma_f32_16x16x16bf16_1k(a, b, c, 0, 0, 0);
}
#else
static __device__ __forceinline__ float4v mfma16(short4v a, short4v b, float4v c){
  float4v d;
  asm volatile("v_mfma_f32_16x16x16_bf16 %0, %1, %2, %3\n\ts_nop 7\n\ts_nop 7"
               : "=v"(d) : "v"(a), "v"(b), "v"(c));
  return d;
}
#endif
static __device__ __forceinline__ float4v mfma32(short8v a, short8v b, float4v c){
  return __builtin_amdgcn_mfma_f32_16x16x32_bf16(a, b, c, 0, 0, 0);
}

// ---------------- merged weight prep + bias folding ----------------
__global__ __launch_bounds__(256) void k_prep2(
    const float* __restrict__ Wq, const float* __restrict__ Wk, const float* __restrict__ Wv,
    const float* __restrict__ Wp, const float* __restrict__ W1, const float* __restrict__ W2,
    const float* __restrict__ l1g, const float* __restrict__ l2g,
    const float* __restrict__ l1b, const float* __restrict__ l2b,
    const float* __restrict__ b1, const float* __restrict__ Wc1, const float* __restrict__ lnfg,
    const float* __restrict__ lnfb, const float* __restrict__ bc1,
    short* __restrict__ qkvT, short* __restrict__ wpT, short* __restrict__ w1T, short* __restrict__ w2T,
    float* __restrict__ bq, float* __restrict__ b1f, float* __restrict__ Wc1s, float* __restrict__ bc1f) {
  const int tid = threadIdx.x;
  const int id = blockIdx.x;
  if (id < 384) {
    __shared__ float tile[64][65];
    int l = id / 96, rr = id % 96;
    const float* src; short* dst; int n0, k0; bool qkvmode; int gsel; float nscale = 1.f;
    if (rr < 48) {
      int tn = rr >> 2, tk = rr & 3;
      n0 = tn*64; k0 = tk*64;
      const float* b3 = (n0 < 256) ? Wq : (n0 < 512 ? Wk : Wv);
      src = b3 + l*65536;
      dst = qkvT + (size_t)l*QSTR*256;
      qkvmode = true; gsel = 1;
      if (n0 < 256) nscale = LC;
    } else {
      int r2 = rr - 48;
      int mat = r2 >> 4, t = r2 & 15;
      int tn = t >> 2, tk = t & 3;
      n0 = tn*64; k0 = tk*64;
      const float* b3 = (mat == 0) ? Wp : (mat == 1 ? W1 : W2);
      src = b3 + l*65536;
      dst = (mat == 0 ? wpT : (mat == 1 ? w1T : w2T)) + l*65536;
      qkvmode = false; gsel = (mat == 1) ? 2 : 0;
    }
    const int cn = tid & 63, rk = tid >> 6;
    #pragma unroll
    for (int i = 0; i < 16; ++i) {
      int kk = rk + i*4;
      int n = n0 + cn, k = k0 + kk;
      float v;
      if (qkvmode) { int nn = n & 255; v = src[((nn>>5)*256 + k)*32 + (nn & 31)]; }
      else         { v = src[k*256 + n]; }
      if (gsel == 1)      v *= l1g[l*256 + k];
      else if (gsel == 2) v *= l2g[l*256 + k];
      tile[kk][cn] = v;
    }
    __syncthreads();
    #pragma unroll
    for (int i = 0; i < 16; ++i) {
      int nn = rk + i*4;
      dst[(size_t)(n0 + nn)*256 + k0 + cn] = f2bs(tile[cn][nn] * nscale);
    }
  } else if (id < 448) {
    __shared__ float red[4][64];
    int bid = id - 384;
    int l = bid >> 4, seg = bid & 15;
    int o = seg*64 + (tid & 63), pp = tid >> 6;
    float s = 0.f;
    if (o < 768) {
      const float* W = (o < 256 ? Wq : (o < 512 ? Wk : Wv)) + l*65536;
      int nn = o & 255, h = nn >> 5, d = nn & 31;
      const float* bv = l1b + l*256;
      for (int k = pp*64; k < pp*64+64; ++k) s = fmaf(bv[k], W[(h*256 + k)*32 + d], s);
    } else {
      const float* W = W1 + l*65536;
      int n = o - 768;
      const float* bv = l2b + l*256;
      for (int k = pp*64; k < pp*64+64; ++k) s = fmaf(bv[k], W[k*256 + n], s);
    }
    red[pp][tid & 63] = s;
    __syncthreads();
    if (tid < 64) {
      float tot = red[0][tid]+red[1][tid]+red[2][tid]+red[3][tid];
      int oo = seg*64 + tid;
      if (oo < 768) bq[l*768 + oo] = tot * (oo < 256 ? LC : 1.f);
      else          b1f[l*256 + (oo-768)] = b1[l*256 + (oo-768)] + tot;
    }
  } else if (id < 512) {
    int base = (id-448)*2048;
    #pragma unroll
    for (int i=0;i<8;++i) {
      int idx2 = base + i*256 + tid;
      Wc1s[idx2] = Wc1[idx2] * lnfg[idx2 >> 9];
    }
  } else {
    for (int u = tid; u < 512; u += 256) {
      float s = bc1[u];
      for (int k=0;k<256;++k) s = fmaf(lnfb[k], Wc1[k*512+u], s);
      bc1f[u] = s;
    }
  }
}

// ---------------- embedding + LN1(layer0) fused: wave per row ----------------
__global__ __launch_bounds__(256) void k_embed2(const int* __restrict__ idx,
    const float* __restrict__ tok, const float* __restrict__ pos,
    float* __restrict__ x, short* __restrict__ y) {
  const int lane = threadIdx.x & 63;
  const int bt = blockIdx.x*4 + (threadIdx.x >> 6);
  const int t = bt & (TDIM-1);
  float4 tv = *(const float4*)&tok[(size_t)idx[bt]*CDIM + lane*4];
  float4 pv = *(const float4*)&pos[(size_t)t*CDIM + lane*4];
  float4 v = make_float4(tv.x+pv.x, tv.y+pv.y, tv.z+pv.z, tv.w+pv.w);
  *(float4*)&x[(size_t)bt*CDIM + lane*4] = v;
  float s1 = (v.x+v.y) + (v.z+v.w);
  float s2 = fmaf(v.x,v.x, fmaf(v.y,v.y, fmaf(v.z,v.z, v.w*v.w)));
  #pragma unroll
  for (int off=32; off>0; off>>=1) { s1 += __shfl_xor(s1, off, 64); s2 += __shfl_xor(s2, off, 64); }
  float mean = s1*(1.f/CDIM);
  float inv  = rsqrtf(s2*(1.f/CDIM) - mean*mean + 1e-5f);
  float cc = -mean*inv;
  union { unsigned u[2]; short4v s; } o;
  o.u[0] = pkbf(fmaf(v.x,inv,cc), fmaf(v.y,inv,cc));
  o.u[1] = pkbf(fmaf(v.z,inv,cc), fmaf(v.w,inv,cc));
  *(short4v*)&y[(size_t)bt*CDIM + lane*4] = o.s;
}

// ---------------- LDS-free MFMA GEMM (QKV): C = A(bf16) x Bt[N][256](bf16) ----------------
template<int NF, bool BIAS, bool RELU, bool OUTBF16, bool ACCUM>
__global__ __launch_bounds__(64) void k_gemm3(const short* __restrict__ A,
    const short* __restrict__ Bt, const float* __restrict__ bias, void* __restrict__ Cv,
    int outstride) {
  const int lane = threadIdx.x;
  const int q4 = lane >> 4, r = lane & 15;
  const int blockRow = blockIdx.x * 32;
  const int blockCol = blockIdx.y * (NF*16);
  float4v acc[2][NF];
  #pragma unroll
  for (int i=0;i<2;++i)
    #pragma unroll
    for (int j=0;j<NF;++j) acc[i][j] = (float4v){0,0,0,0};
  #pragma unroll
  for (int k0 = 0; k0 < 256; k0 += 32) {
    short8v a0 = *(const short8v*)&A[(size_t)(blockRow +      r)*CDIM + k0 + q4*8];
    short8v a1 = *(const short8v*)&A[(size_t)(blockRow + 16 + r)*CDIM + k0 + q4*8];
    #pragma unroll
    for (int nf=0; nf<NF; ++nf) {
      short8v bf = *(const short8v*)&Bt[(size_t)(blockCol + nf*16 + r)*256 + k0 + q4*8];
      acc[0][nf] = mfma32(a0, bf, acc[0][nf]);
      acc[1][nf] = mfma32(a1, bf, acc[1][nf]);
    }
  }
  #pragma unroll
  for (int mf=0; mf<2; ++mf)
    #pragma unroll
    for (int nf=0; nf<NF; ++nf) {
      int col = blockCol + nf*16 + r;
      float bb = BIAS ? bias[col] : 0.f;
      #pragma unroll
      for (int reg=0; reg<4; ++reg) {
        int row = blockRow + mf*16 + q4*4 + reg;
        float v = acc[mf][nf][reg] + bb;
        if (RELU) v = fmaxf(v, 0.f);
        size_t oi = (size_t)row*outstride + col;
        if (ACCUM)        ((float*)Cv)[oi] += v;
        else if (OUTBF16) ((short*)Cv)[oi] = f2bs(v);
        else              ((float*)Cv)[oi] = v;
      }
    }
}

// ---------------- fused GEMM + residual + LN (Wp path) ----------------
template<bool WRITELN>
__global__ __launch_bounds__(512) void k_gemmres(const short* __restrict__ A,
    const short* __restrict__ Bt, const float* __restrict__ bias,
    float* __restrict__ X, short* __restrict__ Y) {
  __shared__ float S1[32][4], S2[32][4];
  const int tid = threadIdx.x;
  const int w = tid >> 6, lane = tid & 63;
  const int q4 = lane >> 4, r = lane & 15;
  const int wm = w & 1, wn = w >> 1;
  const int row0 = blockIdx.x * 32 + wm*16;
  const int col0 = wn*64;
  float4v acc[4];
  #pragma unroll
  for (int j=0;j<4;++j) acc[j] = (float4v){0,0,0,0};
  #pragma unroll
  for (int k0 = 0; k0 < 256; k0 += 32) {
    short8v a0 = *(const short8v*)&A[(size_t)(row0 + r)*CDIM + k0 + q4*8];
    #pragma unroll
    for (int nf=0; nf<4; ++nf) {
      short8v bf = *(const short8v*)&Bt[(size_t)(col0 + nf*16 + r)*256 + k0 + q4*8];
      acc[nf] = mfma32(a0, bf, acc[nf]);
    }
  }
  float v[4][4];
  float sw1[4], sw2[4];
  #pragma unroll
  for (int reg=0; reg<4; ++reg) {
    int row = row0 + q4*4 + reg;
    float s1 = 0.f, s2 = 0.f;
    #pragma unroll
    for (int nf=0; nf<4; ++nf) {
      int col = col0 + nf*16 + r;
      float t = acc[nf][reg] + bias[col] + X[(size_t)row*CDIM + col];
      v[nf][reg] = t;
      X[(size_t)row*CDIM + col] = t;
      s1 += t; s2 = fmaf(t, t, s2);
    }
    if (WRITELN) {
      #pragma unroll
      for (int off=1; off<16; off<<=1) { s1 += __shfl_xor(s1, off, 64); s2 += __shfl_xor(s2, off, 64); }
      sw1[reg] = s1; sw2[reg] = s2;
    }
  }
  if (WRITELN) {
    if (r == 0) {
      #pragma unroll
      for (int reg=0; reg<4; ++reg) {
        S1[wm*16 + q4*4 + reg][wn] = sw1[reg];
        S2[wm*16 + q4*4 + reg][wn] = sw2[reg];
      }
    }
    __syncthreads();
    #pragma unroll
    for (int reg=0; reg<4; ++reg) {
      int ri = wm*16 + q4*4 + reg;
      float s1 = (S1[ri][0]+S1[ri][1]) + (S1[ri][2]+S1[ri][3]);
      float s2 = (S2[ri][0]+S2[ri][1]) + (S2[ri][2]+S2[ri][3]);
      float mean = s1*(1.f/CDIM);
      float inv  = rsqrtf(s2*(1.f/CDIM) - mean*mean + 1e-5f);
      float cc = -mean*inv;
      int row = row0 + q4*4 + reg;
      #pragma unroll
      for (int nf=0; nf<4; ++nf) {
        int col = col0 + nf*16 + r;
        Y[(size_t)row*CDIM + col] = f2bs(fmaf(v[nf][reg], inv, cc));
      }
    }
  }
}

// ---------------- fused FFN: X' += relu(A x W1t + b1f) x W2t + b2; Y = stdize(X') ----------
template<bool WRITELN>
__global__ __launch_bounds__(512) void k_ffn(const short* __restrict__ A,
    const short* __restrict__ W1t, const float* __restrict__ b1f,
    const short* __restrict__ W2t, const float* __restrict__ b2,
    float* __restrict__ X, short* __restrict__ Y) {
  __shared__ __align__(16) short Gs[32*264];
  __shared__ float S1[32][4], S2[32][4];
  const int tid = threadIdx.x;
  const int w = tid >> 6, lane = tid & 63;
  const int q4 = lane >> 4, r = lane & 15;
  const int wm = w & 1, wn = w >> 1;
  const int row0 = blockIdx.x * 32 + wm*16;
  const int col0 = wn*64;
  float4v acc[4];
  #pragma unroll
  for (int j=0;j<4;++j) acc[j] = (float4v){0,0,0,0};
  #pragma unroll
  for (int k0 = 0; k0 < 256; k0 += 32) {
    short8v a0 = *(const short8v*)&A[(size_t)(row0 + r)*CDIM + k0 + q4*8];
    #pragma unroll
    for (int nf=0; nf<4; ++nf) {
      short8v bf = *(const short8v*)&W1t[(size_t)(col0 + nf*16 + r)*256 + k0 + q4*8];
      acc[nf] = mfma32(a0, bf, acc[nf]);
    }
  }
  #pragma unroll
  for (int nf=0; nf<4; ++nf) {
    int col = col0 + nf*16 + r;
    float bb = b1f[col];
    #pragma unroll
    for (int reg=0; reg<4; ++reg) {
      int rl = wm*16 + q4*4 + reg;
      Gs[rl*264 + col] = f2bs(fmaxf(acc[nf][reg] + bb, 0.f));
    }
  }
  __syncthreads();
  #pragma unroll
  for (int j=0;j<4;++j) acc[j] = (float4v){0,0,0,0};
  #pragma unroll
  for (int k0 = 0; k0 < 256; k0 += 32) {
    short8v a0 = *(const short8v*)&Gs[(wm*16 + r)*264 + k0 + q4*8];
    #pragma unroll
    for (int nf=0; nf<4; ++nf) {
      short8v bf = *(const short8v*)&W2t[(size_t)(col0 + nf*16 + r)*256 + k0 + q4*8];
      acc[nf] = mfma32(a0, bf, acc[nf]);
    }
  }
  float v[4][4];
  float sw1[4], sw2[4];
  #pragma unroll
  for (int reg=0; reg<4; ++reg) {
    int row = row0 + q4*4 + reg;
    float s1 = 0.f, s2 = 0.f;
    #pragma unroll
    for (int nf=0; nf<4; ++nf) {
      int col = col0 + nf*16 + r;
      float t = acc[nf][reg] + b2[col] + X[(size_t)row*CDIM + col];
      v[nf][reg] = t;
      X[(size_t)row*CDIM + col] = t;
      s1 += t; s2 = fmaf(t, t, s2);
    }
    if (WRITELN) {
      #pragma unroll
      for (int off=1; off<16; off<<=1) { s1 += __shfl_xor(s1, off, 64); s2 += __shfl_xor(s2, off, 64); }
      sw1[reg] = s1; sw2[reg] = s2;
    }
  }
  if (WRITELN) {
    if (r == 0) {
      #pragma unroll
      for (int reg=0; reg<4; ++reg) {
        S1[wm*16 + q4*4 + reg][wn] = sw1[reg];
        S2[wm*16 + q4*4 + reg][wn] = sw2[reg];
      }
    }
    __syncthreads();
    #pragma unroll
    for (int reg=0; reg<4; ++reg) {
      int ri = wm*16 + q4*4 + reg;
      float s1 = (S1[ri][0]+S1[ri][1]) + (S1[ri][2]+S1[ri][3]);
      float s2 = (S2[ri][0]+S2[ri][1]) + (S2[ri][2]+S2[ri][3]);
      float mean = s1*(1.f/CDIM);
      float inv  = rsqrtf(s2*(1.f/CDIM) - mean*mean + 1e-5f);
      float cc = -mean*inv;
      int row = row0 + q4*4 + reg;
      #pragma unroll
      for (int nf=0; nf<4; ++nf) {
        int col = col0 + nf*16 + r;
        Y[(size_t)row*CDIM + col] = f2bs(fmaf(v[nf][reg], inv, cc));
      }
    }
  }
}

// ---------------- MFMA flash attention: 128-key tiles, dbuf ----------------
#define KSS 40
#define VTS 140
__global__ __launch_bounds__(512) void k_attn6(const short* __restrict__ qkv,
    short* __restrict__ O) {
  __shared__ __align__(16) short Ks[2][128*KSS];
  __shared__ __align__(16) short Vt[2][32*VTS];
  const int tid = threadIdx.x;
  const int w = tid >> 6, lane = tid & 63;
  const int q4 = lane >> 4, r = lane & 15;
  const int b = blockIdx.z, h = blockIdx.y;
  const int rowbase = blockIdx.x*128 + w*16;
  short8v Qf = *(const short8v*)&qkv[((size_t)(b*TDIM + rowbase + r))*QSTR + h*HSZ + q4*8];
  float4v o0 = {0,0,0,0}, o1 = {0,0,0,0};
  float l0 = 0.f;
  const bool isV = tid >= 256;
  const int t2 = tid & 255;
  const int kkey = t2 >> 1, kd0 = (t2 & 1)*16;
  const int kp = t2 & 63, dg = t2 >> 6;
  const short* kvbase = qkv + (size_t)b*TDIM*QSTR + h*HSZ;
  short8v ka, kb2, va, vb;
  if (isV) {
    va = *(const short8v*)&kvbase[(size_t)(2*kp)*QSTR   + 2*CDIM + dg*8];
    vb = *(const short8v*)&kvbase[(size_t)(2*kp+1)*QSTR + 2*CDIM + dg*8];
  } else {
    ka  = *(const short8v*)&kvbase[(size_t)kkey*QSTR + CDIM + kd0];
    kb2 = *(const short8v*)&kvbase[(size_t)kkey*QSTR + CDIM + kd0 + 8];
  }
  int p = 0;
  for (int s0 = 0; s0 < TDIM; s0 += 128, p ^= 1) {
    if (isV) {
      union { short8v s; unsigned u[4]; } A, C;
      A.s = va; C.s = vb;
      #pragma unroll
      for (int j=0;j<4;++j) {
        *(unsigned*)&Vt[p][(dg*8+2*j  )*VTS + 2*kp] = __builtin_amdgcn_perm(C.u[j], A.u[j], 0x05040100u);
        *(unsigned*)&Vt[p][(dg*8+2*j+1)*VTS + 2*kp] = __builtin_amdgcn_perm(C.u[j], A.u[j], 0x07060302u);
      }
    } else {
      *(short8v*)&Ks[p][kkey*KSS + kd0]     = ka;
      *(short8v*)&Ks[p][kkey*KSS + kd0 + 8] = kb2;
    }
    if (s0 + 128 < TDIM) {
      const short* nb = kvbase + (size_t)(s0+128)*QSTR;
      if (isV) {
        va = *(const short8v*)&nb[(size_t)(2*kp)*QSTR   + 2*CDIM + dg*8];
        vb = *(const short8v*)&nb[(size_t)(2*kp+1)*QSTR + 2*CDIM + dg*8];
      } else {
        ka  = *(const short8v*)&nb[(size_t)kkey*QSTR + CDIM + kd0];
        kb2 = *(const short8v*)&nb[(size_t)kkey*QSTR + CDIM + kd0 + 8];
      }
    }
    __syncthreads();
    #pragma unroll
    for (int ks = 0; ks < 8; ++ks) {
      short8v Kf = *(const short8v*)&Ks[p][(ks*16 + r)*KSS + q4*8];
      float4v sv = mfma32(Kf, Qf, (float4v){0,0,0,0});
      short4v Vf0 = *(const short4v*)&Vt[p][r*VTS + ks*16 + q4*4];
      short4v Vf1 = *(const short4v*)&Vt[p][(16+r)*VTS + ks*16 + q4*4];
      float p0 = fexp2(sv[0]), p1 = fexp2(sv[1]);
      float p2 = fexp2(sv[2]), p3 = fexp2(sv[3]);
      l0 += (p0+p1) + (p2+p3);
      union { unsigned u[2]; short4v s; } P;
      P.u[0] = pkbf(p0, p1); P.u[1] = pkbf(p2, p3);
      o0 = mfma16(P.s, Vf0, o0);
      o1 = mfma16(P.s, Vf1, o1);
    }
  }
  l0 += __shfl_xor(l0, 16, 64); l0 += __shfl_xor(l0, 32, 64);
  #pragma unroll
  for (int reg=0; reg<4; ++reg) {
    int qrow = q4*4 + reg;
    float i0 = 1.f / __shfl(l0, qrow, 64);
    short* op = O + ((size_t)(b*TDIM + rowbase + qrow))*CDIM + h*HSZ;
    op[r]    = f2bs(o0[reg]*i0);
    op[16+r] = f2bs(o1[reg]*i0);
  }
}

// ---------------- fused final-LN + mean-pool ----------------
__global__ __launch_bounds__(256) void k_poolln(const float* __restrict__ X, float* __restrict__ part) {
  __shared__ float red[4][256];
  int b = blockIdx.x >> 3, chunk = blockIdx.x & 7;
  int wv = threadIdx.x >> 6, lane = threadIdx.x & 63;
  int base = b*TDIM + chunk*256 + wv*64;
  float a0=0,a1=0,a2=0,a3=0;
  for (int rr=0; rr<64; ++rr) {
    float4 v = *(const float4*)&X[(size_t)(base+rr)*CDIM + lane*4];
    float s1 = (v.x+v.y)+(v.z+v.w);
    float s2 = fmaf(v.x,v.x, fmaf(v.y,v.y, fmaf(v.z,v.z, v.w*v.w)));
    #pragma unroll
    for (int off=32; off>0; off>>=1) { s1 += __shfl_xor(s1,off,64); s2 += __shfl_xor(s2,off,64); }
    float mean = s1*(1.f/256.f);
    float inv  = rsqrtf(s2*(1.f/256.f) - mean*mean + 1e-5f);
    a0 = fmaf(v.x-mean, inv, a0); a1 = fmaf(v.y-mean, inv, a1);
    a2 = fmaf(v.z-mean, inv, a2); a3 = fmaf(v.w-mean, inv, a3);
  }
  red[wv][lane*4+0]=a0; red[wv][lane*4+1]=a1; red[wv][lane*4+2]=a2; red[wv][lane*4+3]=a3;
  __syncthreads();
  int c = threadIdx.x;
  part[blockIdx.x*256 + c] = (red[0][c]+red[1][c]+red[2][c]+red[3][c]) * (1.f/2048.f);
}

// ---------------- fused classifier ----------------
__global__ __launch_bounds__(512) void k_cls(const float* __restrict__ part,
    const float* __restrict__ Wc1s, const float* __restrict__ bc1f,
    const float* __restrict__ Wc2, const float* __restrict__ bc2, float* __restrict__ out) {
  __shared__ float se[4][256];
  __shared__ float sh[4][512];
  __shared__ float red[160];
  __shared__ float sl[40];
  const int t = threadIdx.x;
  for (int j=t; j<1024; j+=512) {
    int b = j >> 8, c = j & 255;
    float s = 0.f;
    #pragma unroll
    for (int ch=0; ch<8; ++ch) s += part[(b*8+ch)*256 + c];
    se[b][c] = s;
  }
  __syncthreads();
  {
    float bb = bc1f[t];
    float a0=bb, a1=bb, a2=bb, a3=bb;
    for (int c=0; c<256; ++c) {
      float w2 = Wc1s[c*512 + t];
      a0 = fmaf(se[0][c], w2, a0); a1 = fmaf(se[1][c], w2, a1);
      a2 = fmaf(se[2][c], w2, a2); a3 = fmaf(se[3][c], w2, a3);
    }
    sh[0][t]=fmaxf(a0,0.f); sh[1][t]=fmaxf(a1,0.f);
    sh[2][t]=fmaxf(a2,0.f); sh[3][t]=fmaxf(a3,0.f);
  }
  __syncthreads();
  if (t < 160) {
    int o = t >> 2, pp = t & 3;
    int b = o / 10, j = o - b*10;
    const float* hp = &sh[b][pp*128];
    float s = 0.f;
    #pragma unroll 8
    for (int u=0; u<128; ++u) s = fmaf(hp[u], Wc2[(pp*128+u)*10 + j], s);
    red[t] = s;
  }
  __syncthreads();
  if (t < 40) sl[t] = (red[t*4]+red[t*4+1]) + (red[t*4+2]+red[t*4+3]) + bc2[t%10];
  __syncthreads();
  if (t < 4) {
    float mx = -1e30f;
    for (int j=0;j<10;++j) mx = fmaxf(mx, sl[t*10+j]);
    float e[10], sum = 0.f;
    for (int j=0;j<10;++j) { e[j] = __expf(sl[t*10+j]-mx); sum += e[j]; }
    float inv = 1.f/sum;
    for (int j=0;j<10;++j) out[t*10+j] = e[j]*inv;
  }
}

extern "C" void kernel_launch(void* const* d_in, const int* in_sizes, int n_in,
                              void* d_out, int out_size, void* d_ws, size_t ws_size,
                              hipStream_t stream) {
  const int*   idx = (const int*)d_in[0];
  const float* tok = (const float*)d_in[1];
  const float* pos = (const float*)d_in[2];
  const float* Wq  = (const float*)d_in[3];
  const float* Wk  = (const float*)d_in[4];
  const float* Wv  = (const float*)d_in[5];
  const float* Wp  = (const float*)d_in[6];
  const float* bp  = (const float*)d_in[7];
  const float* l1g = (const float*)d_in[8];
  const float* l1b = (const float*)d_in[9];
  const float* l2g = (const float*)d_in[10];
  const float* l2b = (const float*)d_in[11];
  const float* W1  = (const float*)d_in[12];
  const float* b1  = (const float*)d_in[13];
  const float* W2  = (const float*)d_in[14];
  const float* b2  = (const float*)d_in[15];
  const float* lfg = (const float*)d_in[16];
  const float* lfb = (const float*)d_in[17];
  const float* Wc1 = (const float*)d_in[18];
  const float* bc1 = (const float*)d_in[19];
  const float* Wc2 = (const float*)d_in[20];
  const float* bc2 = (const float*)d_in[21];

  char* p = (char*)d_ws;
  float* xb   = (float*)p;              p += (size_t)BUF*4;
  short* hb   = (short*)p;              p += (size_t)BUF*2;
  short* qkvb = (short*)p;              p += (size_t)NTOK*QSTR*2;
  float* part = (float*)p;              p += 32*256*4;
  short* wqkvT = (short*)p;             p += (size_t)LNUM*QSTR*256*2;
  short* wpT   = (short*)p;             p += (size_t)LNUM*65536*2;
  short* w1T   = (short*)p;             p += (size_t)LNUM*65536*2;
  short* w2T   = (short*)p;             p += (size_t)LNUM*65536*2;
  float* bq    = (float*)p;             p += (size_t)LNUM*768*4;
  float* b1f   = (float*)p;             p += (size_t)LNUM*256*4;
  float* Wc1s  = (float*)p;             p += (size_t)256*512*4;
  float* bc1f  = (float*)p;             p += 512*4;

  k_prep2<<<513, 256, 0, stream>>>(Wq, Wk, Wv, Wp, W1, W2, l1g, l2g, l1b, l2b,
                                   b1, Wc1, lfg, lfb, bc1,
                                   wqkvT, wpT, w1T, w2T, bq, b1f, Wc1s, bc1f);
  k_embed2<<<NTOK/4, 256, 0, stream>>>(idx, tok, pos, xb, hb);
  for (int l = 0; l < LNUM; ++l) {
    k_gemm3<4,true,false,true,false><<<dim3(256,12), 64, 0, stream>>>(
        hb, wqkvT + (size_t)l*QSTR*256, bq + l*768, qkvb, QSTR);
    k_attn6<<<dim3(16, HDIM, BDIM), 512, 0, stream>>>(qkvb, hb);
    k_gemmres<true><<<256, 512, 0, stream>>>(
        hb, wpT + (size_t)l*65536, bp + l*CDIM, xb, hb);
    if (l < LNUM-1) {
      k_ffn<true><<<256, 512, 0, stream>>>(
          hb, w1T + (size_t)l*65536, b1f + l*CDIM, w2T + (size_t)l*65536, b2 + l*CDIM, xb, hb);
    } else {
      k_ffn<false><<<256, 512, 0, stream>>>(
          hb, w1T + (size_t)l*65536, b1f + l*CDIM, w2T + (size_t)l*65536, b2 + l*CDIM, xb, hb);
    }
  }
  k_poolln<<<32, 256, 0, stream>>>(xb, part);
  k_cls<<<1, 512, 0, stream>>>(part, Wc1s, bc1f, Wc2, bc2, (float*)d_out);
}